// Round 1
// baseline (353.766 us; speedup 1.0000x reference)
//
#include <hip/hip_runtime.h>
#include <cstdint>
#include <cstddef>

#define HW   4096
#define IMG  64
#define DIMC 192
#define NH   4
#define CH   48
#define CPAD 64

typedef __bf16 bf16x8 __attribute__((ext_vector_type(8)));
typedef float  f32x4  __attribute__((ext_vector_type(4)));

__device__ __forceinline__ unsigned short f2bf(float f) {
  unsigned int u = __builtin_bit_cast(unsigned int, f);
  u = (u + 0x7FFFu + ((u >> 16) & 1u)) >> 16;   // RNE
  return (unsigned short)u;
}

__device__ __forceinline__ f32x4 mfma16(bf16x8 a, bf16x8 b, f32x4 c) {
  return __builtin_amdgcn_mfma_f32_16x16x32_bf16(a, b, c, 0, 0, 0);
}

// ---------------------------------------------------------------------------
// K1/K5: pointwise (1x1) conv as GEMM: C[b][oc][p] = sum_ic W[oc][ic]*X[b][ic][p]
// block 256, each thread 4 px, OC tile = 8. Grid: (HW/1024, OC/8, B)
// ---------------------------------------------------------------------------
__global__ __launch_bounds__(256) void pw_conv_kernel(
    const float* __restrict__ X, const float* __restrict__ W,
    float* __restrict__ C, int IC, int OC) {
  __shared__ float Wl[8 * 192];
  const int tid = threadIdx.x;
  const int oct = blockIdx.y;
  const int b   = blockIdx.z;
  const int nW = 8 * IC;
  for (int i = tid; i < nW; i += 256) Wl[i] = W[(size_t)oct * 8 * IC + i];
  __syncthreads();

  const int px = blockIdx.x * 1024 + tid * 4;
  const float* Xb = X + (size_t)b * IC * HW + px;
  float acc[8][4] = {};
  #pragma unroll 4
  for (int ic = 0; ic < IC; ++ic) {
    const float4 xv = *(const float4*)(Xb + (size_t)ic * HW);
    #pragma unroll
    for (int j = 0; j < 8; ++j) {
      const float w = Wl[j * IC + ic];
      acc[j][0] += w * xv.x; acc[j][1] += w * xv.y;
      acc[j][2] += w * xv.z; acc[j][3] += w * xv.w;
    }
  }
  float* Cb = C + ((size_t)b * OC + oct * 8) * HW + px;
  #pragma unroll
  for (int j = 0; j < 8; ++j) {
    float4 o4; o4.x = acc[j][0]; o4.y = acc[j][1]; o4.z = acc[j][2]; o4.w = acc[j][3];
    *(float4*)(Cb + (size_t)j * HW) = o4;
  }
}

// ---------------------------------------------------------------------------
// K2: depthwise 3x3, stride 1, zero pad 1. Grid: (B*576, 4), block 256.
// ---------------------------------------------------------------------------
__global__ __launch_bounds__(256) void dw_conv_kernel(
    const float* __restrict__ X, const float* __restrict__ W,
    float* __restrict__ Y) {
  const int bc = blockIdx.x;            // b*576 + ch
  const int ch = bc % 576;
  const int tid = threadIdx.x;
  const int x = tid & 63;
  const int y0 = blockIdx.y * 16 + (tid >> 6);
  float w[9];
  #pragma unroll
  for (int i = 0; i < 9; ++i) w[i] = W[ch * 9 + i];
  const float* Xb = X + (size_t)bc * HW;
  float* Yb = Y + (size_t)bc * HW;
  #pragma unroll
  for (int i = 0; i < 4; ++i) {
    const int y = y0 + i * 4;
    float s = 0.f;
    #pragma unroll
    for (int dy = -1; dy <= 1; ++dy) {
      const int yy = y + dy;
      #pragma unroll
      for (int dx = -1; dx <= 1; ++dx) {
        const int xx = x + dx;
        const bool ok = (yy >= 0) && (yy < IMG) && (xx >= 0) && (xx < IMG);
        const float v = ok ? Xb[yy * IMG + xx] : 0.f;
        s += w[(dy + 1) * 3 + (dx + 1)] * v;
      }
    }
    Yb[y * IMG + x] = s;
  }
}

// ---------------------------------------------------------------------------
// K3: l2norm(q)*temp, l2norm(k), cast; pack
//   Qr/Kr: [bh][p][CPAD] bf16 row-major (c padded 48->64 with zeros)
//   Vc:    [bh][c][p]    bf16 channel-major
// Grid: (16, NH, B), block 256 (one px per thread)
// ---------------------------------------------------------------------------
__global__ __launch_bounds__(256) void norm_pack_kernel(
    const float* __restrict__ Dw, const float* __restrict__ temp,
    unsigned short* __restrict__ Qr, unsigned short* __restrict__ Kr,
    unsigned short* __restrict__ Vc) {
  const int px = blockIdx.x * 256 + threadIdx.x;
  const int h = blockIdx.y, b = blockIdx.z;
  const int bh = b * NH + h;
  float v[CH];

  { // Q (temperature folded in)
    const float* base = Dw + ((size_t)b * 576 + h * CH) * HW + px;
    float ss = 0.f;
    #pragma unroll
    for (int j = 0; j < CH; ++j) { v[j] = base[(size_t)j * HW]; ss += v[j] * v[j]; }
    const float sc = temp[h] / fmaxf(sqrtf(ss), 1e-12f);
    unsigned short* q = Qr + ((size_t)bh * HW + px) * CPAD;
    #pragma unroll
    for (int j = 0; j < CH; ++j) q[j] = f2bf(v[j] * sc);
    #pragma unroll
    for (int j = CH; j < CPAD; ++j) q[j] = 0;
  }
  { // K
    const float* base = Dw + ((size_t)b * 576 + DIMC + h * CH) * HW + px;
    float ss = 0.f;
    #pragma unroll
    for (int j = 0; j < CH; ++j) { v[j] = base[(size_t)j * HW]; ss += v[j] * v[j]; }
    const float sc = 1.0f / fmaxf(sqrtf(ss), 1e-12f);
    unsigned short* k = Kr + ((size_t)bh * HW + px) * CPAD;
    #pragma unroll
    for (int j = 0; j < CH; ++j) k[j] = f2bf(v[j] * sc);
    #pragma unroll
    for (int j = CH; j < CPAD; ++j) k[j] = 0;
  }
  { // V
    const float* base = Dw + ((size_t)b * 576 + 2 * DIMC + h * CH) * HW + px;
    #pragma unroll
    for (int j = 0; j < CH; ++j)
      Vc[((size_t)bh * CH + j) * HW + px] = f2bf(base[(size_t)j * HW]);
  }
}

// ---------------------------------------------------------------------------
// K4: flash attention, bf16 MFMA 16x16x32.
// Grid (bh=8, qt=64) -> XCD i owns bh=i (K/V stay in that XCD's L2).
// Block 256 = 4 independent waves; each wave owns 16 queries.
// Online softmax in C-layout regs; P goes through padded LDS tile (stride 72
// bf16 -> 2-way banks on b128 reads) to become the PV A-fragment.
// ---------------------------------------------------------------------------
__global__ __launch_bounds__(256) void flash_kernel(
    const unsigned short* __restrict__ Qr,
    const unsigned short* __restrict__ Kr,
    const unsigned short* __restrict__ Vc,
    float* __restrict__ Oc) {
  __shared__ __align__(16) unsigned short Plds[4][2][16 * 72];
  const int tid  = threadIdx.x;
  const int lane = tid & 63;
  const int wv   = tid >> 6;
  const int l15  = lane & 15, l4 = lane >> 4;
  const int bh = blockIdx.x;          // 0..7
  const int qt = blockIdx.y;          // 0..63
  const int qb = qt * 64 + wv * 16;

  const unsigned short* Qb = Qr + (size_t)bh * HW * CPAD;
  const unsigned short* Kb = Kr + (size_t)bh * HW * CPAD;
  const unsigned short* Vb = Vc + (size_t)bh * CH * HW;

  // A-fragments of Q: lane holds Q[qb + (l&15)][(l>>4)*8 + 0..7] (+32 for chunk1)
  const bf16x8 qa0 = *(const bf16x8*)(Qb + (size_t)(qb + l15) * CPAD + l4 * 8);
  const bf16x8 qa1 = *(const bf16x8*)(Qb + (size_t)(qb + l15) * CPAD + 32 + l4 * 8);

  f32x4 o0 = {0.f, 0.f, 0.f, 0.f}, o1 = o0, o2 = o0;
  float mr[4] = {-1e30f, -1e30f, -1e30f, -1e30f};
  float lr[4] = {0.f, 0.f, 0.f, 0.f};

  for (int kt = 0; kt < HW; kt += 64) {
    // ---- S = Q K^T for 16q x 64k ----
    f32x4 s[4];
    #pragma unroll
    for (int n = 0; n < 4; ++n) {
      const unsigned short* kp = Kb + (size_t)(kt + n * 16 + l15) * CPAD + l4 * 8;
      const bf16x8 b0 = *(const bf16x8*)kp;
      const bf16x8 b1 = *(const bf16x8*)(kp + 32);
      f32x4 z = {0.f, 0.f, 0.f, 0.f};
      z = mfma16(qa0, b0, z);
      s[n] = mfma16(qa1, b1, z);
    }
    // C layout: lane holds S[q = l4*4 + r][k = kt + n*16 + l15]
    const int pb = (kt >> 6) & 1;
    #pragma unroll
    for (int r = 0; r < 4; ++r) {
      float mx = fmaxf(fmaxf(s[0][r], s[1][r]), fmaxf(s[2][r], s[3][r]));
      mx = fmaxf(mx, __shfl_xor(mx, 1));
      mx = fmaxf(mx, __shfl_xor(mx, 2));
      mx = fmaxf(mx, __shfl_xor(mx, 4));
      mx = fmaxf(mx, __shfl_xor(mx, 8));
      const float mnew = fmaxf(mr[r], mx);
      const float corr = __expf(mr[r] - mnew);
      mr[r] = mnew;
      float sum = 0.f;
      #pragma unroll
      for (int n = 0; n < 4; ++n) {
        const float p = __expf(s[n][r] - mnew);
        s[n][r] = p;
        sum += p;
      }
      sum += __shfl_xor(sum, 1);
      sum += __shfl_xor(sum, 2);
      sum += __shfl_xor(sum, 4);
      sum += __shfl_xor(sum, 8);
      lr[r] = lr[r] * corr + sum;
      o0[r] *= corr; o1[r] *= corr; o2[r] *= corr;
      #pragma unroll
      for (int n = 0; n < 4; ++n)
        Plds[wv][pb][(l4 * 4 + r) * 72 + n * 16 + l15] = f2bf(s[n][r]);
    }
    __syncthreads();
    // ---- O += P V ----
    #pragma unroll
    for (int kc = 0; kc < 2; ++kc) {
      const bf16x8 pa = *(const bf16x8*)&Plds[wv][pb][l15 * 72 + kc * 32 + l4 * 8];
      const unsigned short* vp = Vb + (size_t)l15 * HW + kt + kc * 32 + l4 * 8;
      o0 = mfma16(pa, *(const bf16x8*)(vp), o0);
      o1 = mfma16(pa, *(const bf16x8*)(vp + 16 * HW), o1);
      o2 = mfma16(pa, *(const bf16x8*)(vp + 32 * HW), o2);
    }
  }
  const int b = bh >> 2, h = bh & 3;
  float* Ob = Oc + ((size_t)b * DIMC + h * CH) * HW + qb;
  float inv[4];
  #pragma unroll
  for (int r = 0; r < 4; ++r) inv[r] = 1.0f / lr[r];
  #pragma unroll
  for (int r = 0; r < 4; ++r) {
    Ob[(size_t)(0 * 16 + l15) * HW + l4 * 4 + r] = o0[r] * inv[r];
    Ob[(size_t)(1 * 16 + l15) * HW + l4 * 4 + r] = o1[r] * inv[r];
    Ob[(size_t)(2 * 16 + l15) * HW + l4 * 4 + r] = o2[r] * inv[r];
  }
}

// ---------------------------------------------------------------------------
extern "C" void kernel_launch(void* const* d_in, const int* in_sizes, int n_in,
                              void* d_out, int out_size, void* d_ws, size_t ws_size,
                              hipStream_t stream) {
  const float* x      = (const float*)d_in[0];
  const float* qkv_w  = (const float*)d_in[1];
  const float* dw_w   = (const float*)d_in[2];
  const float* proj_w = (const float*)d_in[3];
  const float* temp   = (const float*)d_in[4];

  char* ws = (char*)d_ws;
  float*          qkv_f32 = (float*)(ws);                      // 18,874,368 B
  float*          dw_f32  = (float*)(ws + 18874368);           // 18,874,368 B
  unsigned short* Qr      = (unsigned short*)(ws + 37748736);  //  4,194,304 B
  unsigned short* Kr      = (unsigned short*)(ws + 41943040);  //  4,194,304 B
  unsigned short* Vc      = (unsigned short*)(ws + 46137344);  //  3,145,728 B
  float*          attn    = (float*)(ws + 49283072);           //  6,291,456 B

  // 1) qkv 1x1 conv: [2,192,4096] -> [2,576,4096]
  pw_conv_kernel<<<dim3(4, 72, 2), 256, 0, stream>>>(x, qkv_w, qkv_f32, 192, 576);
  // 2) depthwise 3x3
  dw_conv_kernel<<<dim3(1152, 4), 256, 0, stream>>>(qkv_f32, dw_w, dw_f32);
  // 3) l2norm + temperature + bf16 pack
  norm_pack_kernel<<<dim3(16, NH, 2), 256, 0, stream>>>(dw_f32, temp, Qr, Kr, Vc);
  // 4) flash attention (bf16 MFMA)
  flash_kernel<<<dim3(8, 64), 256, 0, stream>>>(Qr, Kr, Vc, attn);
  // 5) proj 1x1 conv -> d_out
  pw_conv_kernel<<<dim3(4, 24, 2), 256, 0, stream>>>(attn, proj_w, (float*)d_out, 192, 192);
}

// Round 2
// 176.007 us; speedup vs baseline: 2.0100x; 2.0100x over previous
//
#include <hip/hip_runtime.h>
#include <cstdint>
#include <cstddef>

#define HW    4096
#define IMG   64
#define DIMC  192
#define NH    4
#define CH    48
#define CPAD  64
#define KVSPLIT 2
#define NTILE (HW / 64 / KVSPLIT)

typedef __bf16 bf16x8 __attribute__((ext_vector_type(8)));
typedef float  f32x4  __attribute__((ext_vector_type(4)));
typedef unsigned short u16x8 __attribute__((ext_vector_type(8)));

__device__ __forceinline__ unsigned short f2bf(float f) {
  unsigned int u = __builtin_bit_cast(unsigned int, f);
  u = (u + 0x7FFFu + ((u >> 16) & 1u)) >> 16;   // RNE
  return (unsigned short)u;
}
__device__ __forceinline__ f32x4 mfma16(bf16x8 a, bf16x8 b, f32x4 c) {
  return __builtin_amdgcn_mfma_f32_16x16x32_bf16(a, b, c, 0, 0, 0);
}
__device__ __forceinline__ void gl16(const void* g, void* l) {
  __builtin_amdgcn_global_load_lds(
      (const __attribute__((address_space(1))) unsigned int*)g,
      (__attribute__((address_space(3))) unsigned int*)l, 16, 0, 0);
}

// ---------------------------------------------------------------------------
// K1/K5: pointwise 1x1 conv as GEMM. OC tile = 16. Grid: (4, OC/16, B)
// ---------------------------------------------------------------------------
__global__ __launch_bounds__(256) void pw_conv_kernel(
    const float* __restrict__ X, const float* __restrict__ W,
    float* __restrict__ C, int IC, int OC) {
  __shared__ float Wl[16 * 192];
  const int tid = threadIdx.x;
  const int oct = blockIdx.y;
  const int b   = blockIdx.z;
  const int nW = 16 * IC;
  for (int i = tid; i < nW; i += 256) Wl[i] = W[(size_t)oct * 16 * IC + i];
  __syncthreads();

  const int px = blockIdx.x * 1024 + tid * 4;
  const float* Xb = X + (size_t)b * IC * HW + px;
  float acc[16][4] = {};
  for (int ic = 0; ic < IC; ++ic) {
    const float4 xv = *(const float4*)(Xb + (size_t)ic * HW);
    #pragma unroll
    for (int j = 0; j < 16; ++j) {
      const float w = Wl[j * IC + ic];
      acc[j][0] += w * xv.x; acc[j][1] += w * xv.y;
      acc[j][2] += w * xv.z; acc[j][3] += w * xv.w;
    }
  }
  float* Cb = C + ((size_t)b * OC + oct * 16) * HW + px;
  #pragma unroll
  for (int j = 0; j < 16; ++j) {
    float4 o4; o4.x = acc[j][0]; o4.y = acc[j][1]; o4.z = acc[j][2]; o4.w = acc[j][3];
    *(float4*)(Cb + (size_t)j * HW) = o4;
  }
}

// ---------------------------------------------------------------------------
// K2: depthwise 3x3, stride 1, zero pad 1. Grid: (B*576, 4), block 256.
// ---------------------------------------------------------------------------
__global__ __launch_bounds__(256) void dw_conv_kernel(
    const float* __restrict__ X, const float* __restrict__ W,
    float* __restrict__ Y) {
  const int bc = blockIdx.x;
  const int ch = bc % 576;
  const int tid = threadIdx.x;
  const int x = tid & 63;
  const int y0 = blockIdx.y * 16 + (tid >> 6);
  float w[9];
  #pragma unroll
  for (int i = 0; i < 9; ++i) w[i] = W[ch * 9 + i];
  const float* Xb = X + (size_t)bc * HW;
  float* Yb = Y + (size_t)bc * HW;
  #pragma unroll
  for (int i = 0; i < 4; ++i) {
    const int y = y0 + i * 4;
    float s = 0.f;
    #pragma unroll
    for (int dy = -1; dy <= 1; ++dy) {
      const int yy = y + dy;
      #pragma unroll
      for (int dx = -1; dx <= 1; ++dx) {
        const int xx = x + dx;
        const bool ok = (yy >= 0) && (yy < IMG) && (xx >= 0) && (xx < IMG);
        const float v = ok ? Xb[yy * IMG + xx] : 0.f;
        s += w[(dy + 1) * 3 + (dx + 1)] * v;
      }
    }
    Yb[y * IMG + x] = s;
  }
}

// ---------------------------------------------------------------------------
// K3: l2norm + temperature + bf16 pack with pre-swizzled layouts.
//   Qr: [bh][p][64] linear (c padded 48->64 w/ zeros)
//   Kr: [bh][p][64], 16B granule g stored at g ^ KSWZ(p), KSWZ(p)=(p&3)|((p>>3)&1)<<2
//   Vs: [bh][c][p],  within each 64-key block: k stored at k ^ ((c&7)<<3)
// Grid: (16, NH, B), block 256 (one px per thread)
// ---------------------------------------------------------------------------
__global__ __launch_bounds__(256) void norm_pack2_kernel(
    const float* __restrict__ Dw, const float* __restrict__ temp,
    unsigned short* __restrict__ Qr, unsigned short* __restrict__ Kr,
    unsigned short* __restrict__ Vs) {
  const int px = blockIdx.x * 256 + threadIdx.x;
  const int h = blockIdx.y, b = blockIdx.z;
  const int bh = b * NH + h;
  const int ksw = (px & 3) | (((px >> 3) & 1) << 2);
  const u16x8 zz = {0, 0, 0, 0, 0, 0, 0, 0};
  float v[CH];

  { // Q (temperature folded in), linear granules
    const float* base = Dw + ((size_t)b * 576 + h * CH) * HW + px;
    float ss = 0.f;
    #pragma unroll
    for (int j = 0; j < CH; ++j) { v[j] = base[(size_t)j * HW]; ss += v[j] * v[j]; }
    const float sc = temp[h] / fmaxf(sqrtf(ss), 1e-12f);
    u16x8 gr[8];
    #pragma unroll
    for (int g = 0; g < 6; ++g)
      #pragma unroll
      for (int j = 0; j < 8; ++j) gr[g][j] = f2bf(v[g * 8 + j] * sc);
    gr[6] = zz; gr[7] = zz;
    unsigned short* qrow = Qr + ((size_t)bh * HW + px) * CPAD;
    #pragma unroll
    for (int g = 0; g < 8; ++g) *(u16x8*)(qrow + g * 8) = gr[g];
  }
  { // K, swizzled granule positions
    const float* base = Dw + ((size_t)b * 576 + DIMC + h * CH) * HW + px;
    float ss = 0.f;
    #pragma unroll
    for (int j = 0; j < CH; ++j) { v[j] = base[(size_t)j * HW]; ss += v[j] * v[j]; }
    const float sc = 1.0f / fmaxf(sqrtf(ss), 1e-12f);
    u16x8 gr[8];
    #pragma unroll
    for (int g = 0; g < 6; ++g)
      #pragma unroll
      for (int j = 0; j < 8; ++j) gr[g][j] = f2bf(v[g * 8 + j] * sc);
    gr[6] = zz; gr[7] = zz;
    unsigned short* krow = Kr + ((size_t)bh * HW + px) * CPAD;
    #pragma unroll
    for (int g = 0; g < 8; ++g) *(u16x8*)(krow + (g ^ ksw) * 8) = gr[g];
  }
  { // V channel-major, swizzled within 64-key blocks
    const float* base = Dw + ((size_t)b * 576 + 2 * DIMC + h * CH) * HW + px;
    const int kt = px & ~63, kl = px & 63;
    #pragma unroll
    for (int c = 0; c < CH; ++c)
      Vs[((size_t)bh * CH + c) * HW + kt + (kl ^ ((c & 7) << 3))] = f2bf(base[(size_t)c * HW]);
  }
}

// ---------------------------------------------------------------------------
// K4: flash attention v2. Swapped QK^T (S^T=mfma(K,Q)) with key-permuted A rows
// so softmax + P->PV are fully lane-local. K/V double-buffered in LDS via
// global_load_lds (pre-swizzled global layouts -> conflict-spread ds_read_b128).
// 4 waves x 32q per block; KV split across blockIdx.z with combine pass.
// Grid (8, 32, KVSPLIT): linear id % 8 == bh -> each head L2-resident per XCD.
// ---------------------------------------------------------------------------
__global__ __launch_bounds__(256, 2) void flash2_kernel(
    const unsigned short* __restrict__ Qr,
    const unsigned short* __restrict__ Kr,
    const unsigned short* __restrict__ Vs,
    float* __restrict__ Opart, float* __restrict__ Mpart, float* __restrict__ Lpart) {
  __shared__ __align__(16) unsigned short Kl[2][64 * 64];   // 2 x 8KB
  __shared__ __align__(16) unsigned short Vl[2][48 * 64];   // 2 x 6KB
  const int tid = threadIdx.x;
  const int lane = tid & 63, wv = tid >> 6;
  const int l15 = lane & 15, l4 = lane >> 4;
  const int bh = blockIdx.x, qt = blockIdx.y, sp = blockIdx.z;
  const int qb = qt * 128 + wv * 32;

  // Q B-fragments (fixed per wave): lane holds Q[q=qg*16+l15][ch=h*32+l4*8+j]
  const unsigned short* Qb = Qr + ((size_t)bh * HW + qb) * CPAD;
  bf16x8 qf[2][2];
  #pragma unroll
  for (int qg = 0; qg < 2; ++qg)
    #pragma unroll
    for (int h = 0; h < 2; ++h)
      qf[qg][h] = *(const bf16x8*)(Qb + (size_t)(qg * 16 + l15) * CPAD + h * 32 + l4 * 8);

  const char* kbase = (const char*)Kr + ((size_t)bh * HW + (size_t)sp * (HW / KVSPLIT)) * 128;
  const char* vbase = (const char*)Vs + (size_t)bh * CH * HW * 2;
  const size_t vsp = (size_t)sp * (HW / KVSPLIT) * 2;

  auto stage = [&](int buf, int t) {
    const char* kg = kbase + (size_t)t * 8192;
    char* kl = (char*)&Kl[buf][0];
    gl16(kg + tid * 16,        kl + tid * 16);
    gl16(kg + 4096 + tid * 16, kl + 4096 + tid * 16);
    const char* vg = vbase + vsp + (size_t)t * 128;
    char* vl = (char*)&Vl[buf][0];
    {
      const int c = tid >> 3, g = tid & 7;
      gl16(vg + (size_t)c * 8192 + g * 16, vl + tid * 16);
    }
    if (tid < 128) {
      const int c = 32 + (tid >> 3), g = tid & 7;
      gl16(vg + (size_t)c * 8192 + g * 16, vl + 4096 + tid * 16);
    }
  };

  f32x4 o[3][2];
  #pragma unroll
  for (int cg = 0; cg < 3; ++cg)
    #pragma unroll
    for (int qg = 0; qg < 2; ++qg) o[cg][qg] = f32x4{0.f, 0.f, 0.f, 0.f};
  float m[2] = {-1e30f, -1e30f}, l[2] = {0.f, 0.f};

  stage(0, 0);
  __syncthreads();
  int cur = 0;
  for (int t = 0; t < NTILE; ++t) {
    if (t + 1 < NTILE) stage(cur ^ 1, t + 1);     // prefetch next tile
    const char* KL = (const char*)&Kl[cur][0];
    const char* VL = (const char*)&Vl[cur][0];

    // ---- S^T = K * Q : s[qg][n], lane holds keys (2kc+(j>>2))*... for q=l15
    f32x4 s[2][4];
    #pragma unroll
    for (int n = 0; n < 4; ++n) {
      const int row = (n >> 1) * 32 + (l15 >> 2) * 8 + (n & 1) * 4 + (l15 & 3);
      const int sw = (l15 & 7) << 4;
      const bf16x8 kf0 = *(const bf16x8*)(KL + row * 128 + ((l4 << 4) ^ sw));
      const bf16x8 kf1 = *(const bf16x8*)(KL + row * 128 + (((4 + l4) << 4) ^ sw));
      #pragma unroll
      for (int qg = 0; qg < 2; ++qg) {
        f32x4 z = {0.f, 0.f, 0.f, 0.f};
        z = mfma16(kf0, qf[qg][0], z);
        s[qg][n] = mfma16(kf1, qf[qg][1], z);
      }
    }

    // ---- online softmax, lane-local + 2 shuffles per qg ----
    #pragma unroll
    for (int qg = 0; qg < 2; ++qg) {
      float e[16];
      #pragma unroll
      for (int n = 0; n < 4; ++n)
        #pragma unroll
        for (int r = 0; r < 4; ++r) e[n * 4 + r] = s[qg][n][r];
      #pragma unroll
      for (int i = 0; i < 8; ++i) e[i] = fmaxf(e[i], e[i + 8]);
      #pragma unroll
      for (int i = 0; i < 4; ++i) e[i] = fmaxf(e[i], e[i + 4]);
      float pm = fmaxf(fmaxf(e[0], e[1]), fmaxf(e[2], e[3]));
      pm = fmaxf(pm, __shfl_xor(pm, 16));
      pm = fmaxf(pm, __shfl_xor(pm, 32));
      const float mnew = fmaxf(m[qg], pm);
      const float corr = __expf(m[qg] - mnew);
      m[qg] = mnew;
      float a[16];
      #pragma unroll
      for (int n = 0; n < 4; ++n)
        #pragma unroll
        for (int r = 0; r < 4; ++r) {
          const float p = __expf(s[qg][n][r] - mnew);
          s[qg][n][r] = p;
          a[n * 4 + r] = p;
        }
      #pragma unroll
      for (int i = 0; i < 8; ++i) a[i] += a[i + 8];
      #pragma unroll
      for (int i = 0; i < 4; ++i) a[i] += a[i + 4];
      float sum = (a[0] + a[1]) + (a[2] + a[3]);
      sum += __shfl_xor(sum, 16);
      sum += __shfl_xor(sum, 32);
      l[qg] = l[qg] * corr + sum;
      #pragma unroll
      for (int cg = 0; cg < 3; ++cg) o[cg][qg] *= corr;
    }

    // ---- O^T += V^T * P^T : P fragment built lane-locally from s regs ----
    #pragma unroll
    for (int kc = 0; kc < 2; ++kc) {
      bf16x8 pb[2];
      #pragma unroll
      for (int qg = 0; qg < 2; ++qg)
        #pragma unroll
        for (int j = 0; j < 8; ++j)
          pb[qg][j] = (__bf16)s[qg][kc * 2 + (j >> 2)][j & 3];
      #pragma unroll
      for (int cg = 0; cg < 3; ++cg) {
        const int vrow = cg * 16 + l15;
        const bf16x8 vf = *(const bf16x8*)(VL + vrow * 128 + (((kc * 4 + l4) ^ (l15 & 7)) << 4));
        #pragma unroll
        for (int qg = 0; qg < 2; ++qg) o[cg][qg] = mfma16(vf, pb[qg], o[cg][qg]);
      }
    }
    __syncthreads();   // drains staging vmcnt + guards buffer reuse
    cur ^= 1;
  }

  // epilogue: unnormalized O^T[c][q], plus m,l per q
  float* Ob = Opart + (size_t)(sp * 8 + bh) * CH * HW;
  #pragma unroll
  for (int cg = 0; cg < 3; ++cg)
    #pragma unroll
    for (int qg = 0; qg < 2; ++qg)
      #pragma unroll
      for (int r = 0; r < 4; ++r)
        Ob[(size_t)(cg * 16 + l4 * 4 + r) * HW + qb + qg * 16 + l15] = o[cg][qg][r];
  if (l4 == 0) {
    #pragma unroll
    for (int qg = 0; qg < 2; ++qg) {
      const size_t ix = (size_t)(sp * 8 + bh) * HW + qb + qg * 16 + l15;
      Mpart[ix] = m[qg];
      Lpart[ix] = l[qg];
    }
  }
}

// ---------------------------------------------------------------------------
// K4b: combine the KV splits. thread = (bh, q). Grid 128 x 256.
// ---------------------------------------------------------------------------
__global__ __launch_bounds__(256) void combine_kernel(
    const float* __restrict__ Opart, const float* __restrict__ Mpart,
    const float* __restrict__ Lpart, float* __restrict__ A) {
  const int idx = blockIdx.x * 256 + threadIdx.x;   // bh*4096 + q
  const int bh = idx >> 12, q = idx & 4095;
  const float m0 = Mpart[idx], m1 = Mpart[8 * HW + idx];
  const float l0 = Lpart[idx], l1 = Lpart[8 * HW + idx];
  const float mg = fmaxf(m0, m1);
  float w0 = __expf(m0 - mg), w1 = __expf(m1 - mg);
  const float inv = 1.f / (w0 * l0 + w1 * l1);
  w0 *= inv; w1 *= inv;
  const int b = bh >> 2, h = bh & 3;
  const float* O0 = Opart + (size_t)bh * CH * HW + q;
  const float* O1 = O0 + (size_t)8 * CH * HW;
  float* Ap = A + ((size_t)b * DIMC + h * CH) * HW + q;
  #pragma unroll
  for (int c = 0; c < CH; ++c)
    Ap[(size_t)c * HW] = w0 * O0[(size_t)c * HW] + w1 * O1[(size_t)c * HW];
}

// ---------------------------------------------------------------------------
extern "C" void kernel_launch(void* const* d_in, const int* in_sizes, int n_in,
                              void* d_out, int out_size, void* d_ws, size_t ws_size,
                              hipStream_t stream) {
  const float* x      = (const float*)d_in[0];
  const float* qkv_w  = (const float*)d_in[1];
  const float* dw_w   = (const float*)d_in[2];
  const float* proj_w = (const float*)d_in[3];
  const float* temp   = (const float*)d_in[4];

  char* ws = (char*)d_ws;
  float*          qkv_f32 = (float*)(ws);                      // [0, 18.9M)
  float*          dw_f32  = (float*)(ws + 18874368);           // [18.9M, 37.7M)
  unsigned short* Qr      = (unsigned short*)(ws + 37748736);  // 4 MB
  unsigned short* Kr      = (unsigned short*)(ws + 41943040);  // 4 MB
  unsigned short* Vs      = (unsigned short*)(ws + 46137344);  // 3 MB
  // after dw_conv, qkv region is dead -> reuse for attention partials
  float*          Opart   = (float*)(ws);                      // 12.58 MB
  float*          Mpart   = (float*)(ws + 12582912);           // 256 KB
  float*          Lpart   = (float*)(ws + 12845056);           // 256 KB
  // after norm_pack, dw region is dead -> reuse for combined attention output
  float*          attn    = (float*)(ws + 18874368);           // 6.29 MB

  // 1) qkv 1x1 conv: [2,192,4096] -> [2,576,4096]
  pw_conv_kernel<<<dim3(4, 36, 2), 256, 0, stream>>>(x, qkv_w, qkv_f32, 192, 576);
  // 2) depthwise 3x3
  dw_conv_kernel<<<dim3(1152, 4), 256, 0, stream>>>(qkv_f32, dw_w, dw_f32);
  // 3) l2norm + temperature + bf16 pack (pre-swizzled layouts)
  norm_pack2_kernel<<<dim3(16, NH, 2), 256, 0, stream>>>(dw_f32, temp, Qr, Kr, Vs);
  // 4) flash attention v2 (KV-split=2)
  flash2_kernel<<<dim3(8, 32, KVSPLIT), 256, 0, stream>>>(Qr, Kr, Vs, Opart, Mpart, Lpart);
  // 4b) combine splits
  combine_kernel<<<dim3(128), 256, 0, stream>>>(Opart, Mpart, Lpart, attn);
  // 5) proj 1x1 conv -> d_out
  pw_conv_kernel<<<dim3(4, 12, 2), 256, 0, stream>>>(attn, proj_w, (float*)d_out, 192, 192);
}

// Round 3
// 141.138 us; speedup vs baseline: 2.5065x; 1.2471x over previous
//
#include <hip/hip_runtime.h>
#include <cstdint>
#include <cstddef>

#define HW    4096
#define IMG   64
#define DIMC  192
#define NH    4
#define CH    48
#define CPAD  64
#define KVSPLIT 4
#define NTILE (HW / 64 / KVSPLIT)
#define LOG2E 1.4426950408889634f

typedef __bf16 bf16x8 __attribute__((ext_vector_type(8)));
typedef float  f32x4  __attribute__((ext_vector_type(4)));
typedef unsigned short u16x8 __attribute__((ext_vector_type(8)));

__device__ __forceinline__ unsigned short f2bf(float f) {
  unsigned int u = __builtin_bit_cast(unsigned int, f);
  u = (u + 0x7FFFu + ((u >> 16) & 1u)) >> 16;   // RNE
  return (unsigned short)u;
}
__device__ __forceinline__ f32x4 mfma16(bf16x8 a, bf16x8 b, f32x4 c) {
  return __builtin_amdgcn_mfma_f32_16x16x32_bf16(a, b, c, 0, 0, 0);
}
__device__ __forceinline__ void gl16(const void* g, void* l) {
  __builtin_amdgcn_global_load_lds(
      (const __attribute__((address_space(1))) unsigned int*)g,
      (__attribute__((address_space(3))) unsigned int*)l, 16, 0, 0);
}

// ---------------------------------------------------------------------------
// P0: pack x -> xb bf16 [b*4096+px][192] (k-major rows), and weights -> bf16.
// Grid 136: blocks 0..127 pack x; blocks 128..135 pack qkv_w + proj_w.
// ---------------------------------------------------------------------------
__global__ __launch_bounds__(256) void pack_kernel(
    const float* __restrict__ x, const float* __restrict__ qkv_w,
    const float* __restrict__ proj_w, unsigned short* __restrict__ xb,
    unsigned short* __restrict__ wqkv, unsigned short* __restrict__ wproj) {
  const int bx = blockIdx.x, tid = threadIdx.x;
  if (bx < 128) {
    const int b = bx >> 6;
    const int px = ((bx & 63) << 6) + (tid & 63);
    const int c0 = (tid >> 6) * 48;
    const float* src = x + ((size_t)b * DIMC + c0) * HW + px;
    u16x8 g[6];
    #pragma unroll
    for (int cc = 0; cc < 6; ++cc)
      #pragma unroll
      for (int j = 0; j < 8; ++j)
        g[cc][j] = f2bf(src[(size_t)(cc * 8 + j) * HW]);
    unsigned short* dst = xb + ((size_t)b * HW + px) * DIMC + c0;
    #pragma unroll
    for (int cc = 0; cc < 6; ++cc) *(u16x8*)(dst + cc * 8) = g[cc];
  } else {
    const int base = (bx - 128) * 256 + tid;
    for (int i = base; i < 576 * 192; i += 2048) wqkv[i] = f2bf(qkv_w[i]);
    for (int i = base; i < 192 * 192; i += 2048) wproj[i] = f2bf(proj_w[i]);
  }
}

// ---------------------------------------------------------------------------
// G1: bf16 MFMA GEMM  C[b][oc][px] = sum_k W[oc][k] * Xb[b][px][k]
// Block: 64 oc x (PF*16) px, 4 waves (wave = 16 oc x PF*16 px). K=192.
// A/B fragments loaded directly from global (L2-resident). No LDS.
// Grid: (OC/64, 4096/(PF*16), B)
// ---------------------------------------------------------------------------
template <int PF>
__global__ __launch_bounds__(256) void wx_gemm_kernel(
    const unsigned short* __restrict__ xb, const unsigned short* __restrict__ wb,
    float* __restrict__ C, int OC) {
  const int tid = threadIdx.x;
  const int lane = tid & 63, wv = tid >> 6;
  const int l15 = lane & 15, l4 = lane >> 4;
  const int oc0 = blockIdx.x * 64 + wv * 16;
  const int px0 = blockIdx.y * (PF * 16);
  const int b   = blockIdx.z;

  const unsigned short* wrow = wb + (size_t)(oc0 + l15) * 192;
  const unsigned short* xrow = xb + ((size_t)b * HW + px0 + l15) * 192;

  f32x4 acc[PF];
  #pragma unroll
  for (int p = 0; p < PF; ++p) acc[p] = f32x4{0.f, 0.f, 0.f, 0.f};

  #pragma unroll
  for (int kc = 0; kc < 6; ++kc) {
    const int ko = kc * 32 + l4 * 8;
    const bf16x8 af = *(const bf16x8*)(wrow + ko);
    #pragma unroll
    for (int p = 0; p < PF; ++p) {
      const bf16x8 bf = *(const bf16x8*)(xrow + (size_t)p * 16 * 192 + ko);
      acc[p] = mfma16(af, bf, acc[p]);
    }
  }
  float* Cb = C + ((size_t)b * OC + oc0) * HW + px0;
  #pragma unroll
  for (int p = 0; p < PF; ++p)
    #pragma unroll
    for (int r = 0; r < 4; ++r)
      Cb[(size_t)(l4 * 4 + r) * HW + p * 16 + l15] = acc[p][r];
}

// ---------------------------------------------------------------------------
// K2: depthwise 3x3 via LDS-tiled rolling-register stencil.
// One block per (b,ch) image; LDS [66][72] fp32 with zero halos.
// ---------------------------------------------------------------------------
__global__ __launch_bounds__(256) void dw_conv2_kernel(
    const float* __restrict__ X, const float* __restrict__ W,
    float* __restrict__ Y) {
  __shared__ float T[66][72];
  const int bc = blockIdx.x;            // b*576 + ch
  const int ch = bc % 576;
  const int tid = threadIdx.x;
  const float* Xb = X + (size_t)bc * HW;
  #pragma unroll
  for (int i = 0; i < 4; ++i) {
    const int idx = i * 256 + tid;      // 0..1023 quads
    const int row = idx >> 4, c4 = (idx & 15) << 2;
    *(float4*)&T[row + 1][c4 + 4] = *(const float4*)(Xb + row * 64 + c4);
  }
  if (tid < 72) { T[0][tid] = 0.f; T[65][tid] = 0.f; }
  if (tid >= 128 && tid < 194) { const int r = tid - 128; T[r][3] = 0.f; T[r][68] = 0.f; }
  float w[9];
  #pragma unroll
  for (int i = 0; i < 9; ++i) w[i] = W[ch * 9 + i];
  __syncthreads();

  const int xx = tid & 63, ys = (tid >> 6) << 4;
  const int c = xx + 4;
  float a0 = T[ys][c - 1],     a1 = T[ys][c],     a2 = T[ys][c + 1];
  float b0 = T[ys + 1][c - 1], b1 = T[ys + 1][c], b2 = T[ys + 1][c + 1];
  float* Yb = Y + (size_t)bc * HW;
  #pragma unroll
  for (int k = 0; k < 16; ++k) {
    const float c0 = T[ys + k + 2][c - 1], c1 = T[ys + k + 2][c], c2 = T[ys + k + 2][c + 1];
    const float s = w[0] * a0 + w[1] * a1 + w[2] * a2
                  + w[3] * b0 + w[4] * b1 + w[5] * b2
                  + w[6] * c0 + w[7] * c1 + w[8] * c2;
    Yb[(ys + k) * 64 + xx] = s;
    a0 = b0; a1 = b1; a2 = b2; b0 = c0; b1 = c1; b2 = c2;
  }
}

// ---------------------------------------------------------------------------
// K3: l2norm + temp*log2e folded into q + bf16 pack (pre-swizzled layouts).
//   Qr: [bh][p][64] linear; Kr: granule g at g^KSWZ(p); Vs: k at k^((c&7)<<3)
// ---------------------------------------------------------------------------
__global__ __launch_bounds__(256) void norm_pack2_kernel(
    const float* __restrict__ Dw, const float* __restrict__ temp,
    unsigned short* __restrict__ Qr, unsigned short* __restrict__ Kr,
    unsigned short* __restrict__ Vs) {
  const int px = blockIdx.x * 256 + threadIdx.x;
  const int h = blockIdx.y, b = blockIdx.z;
  const int bh = b * NH + h;
  const int ksw = (px & 3) | (((px >> 3) & 1) << 2);
  const u16x8 zz = {0, 0, 0, 0, 0, 0, 0, 0};
  float v[CH];

  { // Q (temperature * log2e folded in)
    const float* base = Dw + ((size_t)b * 576 + h * CH) * HW + px;
    float ss = 0.f;
    #pragma unroll
    for (int j = 0; j < CH; ++j) { v[j] = base[(size_t)j * HW]; ss += v[j] * v[j]; }
    const float sc = temp[h] * LOG2E / fmaxf(sqrtf(ss), 1e-12f);
    u16x8 gr[8];
    #pragma unroll
    for (int g = 0; g < 6; ++g)
      #pragma unroll
      for (int j = 0; j < 8; ++j) gr[g][j] = f2bf(v[g * 8 + j] * sc);
    gr[6] = zz; gr[7] = zz;
    unsigned short* qrow = Qr + ((size_t)bh * HW + px) * CPAD;
    #pragma unroll
    for (int g = 0; g < 8; ++g) *(u16x8*)(qrow + g * 8) = gr[g];
  }
  { // K
    const float* base = Dw + ((size_t)b * 576 + DIMC + h * CH) * HW + px;
    float ss = 0.f;
    #pragma unroll
    for (int j = 0; j < CH; ++j) { v[j] = base[(size_t)j * HW]; ss += v[j] * v[j]; }
    const float sc = 1.0f / fmaxf(sqrtf(ss), 1e-12f);
    u16x8 gr[8];
    #pragma unroll
    for (int g = 0; g < 6; ++g)
      #pragma unroll
      for (int j = 0; j < 8; ++j) gr[g][j] = f2bf(v[g * 8 + j] * sc);
    gr[6] = zz; gr[7] = zz;
    unsigned short* krow = Kr + ((size_t)bh * HW + px) * CPAD;
    #pragma unroll
    for (int g = 0; g < 8; ++g) *(u16x8*)(krow + (g ^ ksw) * 8) = gr[g];
  }
  { // V channel-major, swizzled within 64-key blocks
    const float* base = Dw + ((size_t)b * 576 + 2 * DIMC + h * CH) * HW + px;
    const int kt = px & ~63, kl = px & 63;
    #pragma unroll
    for (int c = 0; c < CH; ++c)
      Vs[((size_t)bh * CH + c) * HW + kt + (kl ^ ((c & 7) << 3))] = f2bf(base[(size_t)c * HW]);
  }
}

// ---------------------------------------------------------------------------
// K4: flash attention v3. Static softmax max (|logit| <= |temp|*log2e) baked
// into the MFMA C-init => NO max tracking, NO rescale. KVSPLIT=4.
// Grid (8, 32, 4): 1024 blocks -> 4 blocks/CU, 16 waves/CU.
// ---------------------------------------------------------------------------
__global__ __launch_bounds__(256, 4) void flash3_kernel(
    const unsigned short* __restrict__ Qr,
    const unsigned short* __restrict__ Kr,
    const unsigned short* __restrict__ Vs,
    const float* __restrict__ temp,
    float* __restrict__ Opart, float* __restrict__ Lpart) {
  __shared__ __align__(16) unsigned short Kl[2][64 * 64];   // 2 x 8KB
  __shared__ __align__(16) unsigned short Vl[2][48 * 64];   // 2 x 6KB
  const int tid = threadIdx.x;
  const int lane = tid & 63, wv = tid >> 6;
  const int l15 = lane & 15, l4 = lane >> 4;
  const int bh = blockIdx.x, qt = blockIdx.y, sp = blockIdx.z;
  const int qb = qt * 128 + wv * 32;
  const float m = fabsf(temp[bh & 3]) * LOG2E * 1.05f + 0.1f;  // static logit bound

  const unsigned short* Qb = Qr + ((size_t)bh * HW + qb) * CPAD;
  bf16x8 qf[2][2];
  #pragma unroll
  for (int qg = 0; qg < 2; ++qg)
    #pragma unroll
    for (int hh = 0; hh < 2; ++hh)
      qf[qg][hh] = *(const bf16x8*)(Qb + (size_t)(qg * 16 + l15) * CPAD + hh * 32 + l4 * 8);

  const char* kbase = (const char*)Kr + ((size_t)bh * HW + (size_t)sp * (HW / KVSPLIT)) * 128;
  const char* vbase = (const char*)Vs + (size_t)bh * CH * HW * 2;
  const size_t vsp = (size_t)sp * (HW / KVSPLIT) * 2;

  auto stage = [&](int buf, int t) {
    const char* kg = kbase + (size_t)t * 8192;
    char* kl = (char*)&Kl[buf][0];
    gl16(kg + tid * 16,        kl + tid * 16);
    gl16(kg + 4096 + tid * 16, kl + 4096 + tid * 16);
    const char* vg = vbase + vsp + (size_t)t * 128;
    char* vl = (char*)&Vl[buf][0];
    {
      const int c = tid >> 3, g = tid & 7;
      gl16(vg + (size_t)c * 8192 + g * 16, vl + tid * 16);
    }
    if (tid < 128) {
      const int c = 32 + (tid >> 3), g = tid & 7;
      gl16(vg + (size_t)c * 8192 + g * 16, vl + 4096 + tid * 16);
    }
  };

  f32x4 o[3][2];
  #pragma unroll
  for (int cg = 0; cg < 3; ++cg)
    #pragma unroll
    for (int qg = 0; qg < 2; ++qg) o[cg][qg] = f32x4{0.f, 0.f, 0.f, 0.f};
  float l[2] = {0.f, 0.f};
  const f32x4 zinit = {-m, -m, -m, -m};

  stage(0, 0);
  __syncthreads();
  int cur = 0;
  for (int t = 0; t < NTILE; ++t) {
    if (t + 1 < NTILE) stage(cur ^ 1, t + 1);
    const char* KL = (const char*)&Kl[cur][0];
    const char* VL = (const char*)&Vl[cur][0];

    // ---- S^T - m = K*Q + (-m) ----
    f32x4 s[2][4];
    __builtin_amdgcn_s_setprio(1);
    #pragma unroll
    for (int n = 0; n < 4; ++n) {
      const int row = (n >> 1) * 32 + (l15 >> 2) * 8 + (n & 1) * 4 + (l15 & 3);
      const int sw = (l15 & 7) << 4;
      const bf16x8 kf0 = *(const bf16x8*)(KL + row * 128 + ((l4 << 4) ^ sw));
      const bf16x8 kf1 = *(const bf16x8*)(KL + row * 128 + (((4 + l4) << 4) ^ sw));
      #pragma unroll
      for (int qg = 0; qg < 2; ++qg) {
        f32x4 z = mfma16(kf0, qf[qg][0], zinit);
        s[qg][n] = mfma16(kf1, qf[qg][1], z);
      }
    }
    __builtin_amdgcn_s_setprio(0);

    // ---- softmax numerator: p = exp2(s), row-sum only ----
    #pragma unroll
    for (int qg = 0; qg < 2; ++qg) {
      float a[16];
      #pragma unroll
      for (int n = 0; n < 4; ++n)
        #pragma unroll
        for (int r = 0; r < 4; ++r) {
          const float p = exp2f(s[qg][n][r]);
          s[qg][n][r] = p;
          a[n * 4 + r] = p;
        }
      #pragma unroll
      for (int i = 0; i < 8; ++i) a[i] += a[i + 8];
      #pragma unroll
      for (int i = 0; i < 4; ++i) a[i] += a[i + 4];
      float sum = (a[0] + a[1]) + (a[2] + a[3]);
      sum += __shfl_xor(sum, 16);
      sum += __shfl_xor(sum, 32);
      l[qg] += sum;
    }

    // ---- O^T += V^T * P^T (P fragment built lane-locally) ----
    #pragma unroll
    for (int kc = 0; kc < 2; ++kc) {
      bf16x8 pb[2];
      #pragma unroll
      for (int qg = 0; qg < 2; ++qg)
        #pragma unroll
        for (int j = 0; j < 8; ++j)
          pb[qg][j] = (__bf16)s[qg][kc * 2 + (j >> 2)][j & 3];
      __builtin_amdgcn_s_setprio(1);
      #pragma unroll
      for (int cg = 0; cg < 3; ++cg) {
        const int vrow = cg * 16 + l15;
        const bf16x8 vf = *(const bf16x8*)(VL + vrow * 128 + (((kc * 4 + l4) ^ (l15 & 7)) << 4));
        #pragma unroll
        for (int qg = 0; qg < 2; ++qg) o[cg][qg] = mfma16(vf, pb[qg], o[cg][qg]);
      }
      __builtin_amdgcn_s_setprio(0);
    }
    __syncthreads();
    cur ^= 1;
  }

  float* Ob = Opart + (size_t)(sp * 8 + bh) * CH * HW;
  #pragma unroll
  for (int cg = 0; cg < 3; ++cg)
    #pragma unroll
    for (int qg = 0; qg < 2; ++qg)
      #pragma unroll
      for (int r = 0; r < 4; ++r)
        Ob[(size_t)(cg * 16 + l4 * 4 + r) * HW + qb + qg * 16 + l15] = o[cg][qg][r];
  if (l4 == 0) {
    #pragma unroll
    for (int qg = 0; qg < 2; ++qg)
      Lpart[(size_t)(sp * 8 + bh) * HW + qb + qg * 16 + l15] = l[qg];
  }
}

// ---------------------------------------------------------------------------
// K4b: combine splits (plain sums; shared static m) -> bf16 rows [px][192]
// ---------------------------------------------------------------------------
__global__ __launch_bounds__(256) void combine_kernel(
    const float* __restrict__ Opart, const float* __restrict__ Lpart,
    unsigned short* __restrict__ attnb) {
  const int idx = blockIdx.x * 256 + threadIdx.x;   // bh*4096 + q
  const int bh = idx >> 12, q = idx & 4095;
  float lsum = 0.f;
  #pragma unroll
  for (int sp = 0; sp < KVSPLIT; ++sp) lsum += Lpart[(size_t)(sp * 8 + bh) * HW + q];
  const float inv = 1.f / lsum;
  unsigned short* arow = attnb + ((size_t)(bh >> 2) * HW + q) * DIMC + (bh & 3) * CH;
  u16x8 g[6];
  #pragma unroll
  for (int cc = 0; cc < 6; ++cc) {
    #pragma unroll
    for (int j = 0; j < 8; ++j) {
      const int c = cc * 8 + j;
      float v = 0.f;
      #pragma unroll
      for (int sp = 0; sp < KVSPLIT; ++sp)
        v += Opart[((size_t)(sp * 8 + bh) * CH + c) * HW + q];
      g[cc][j] = f2bf(v * inv);
    }
  }
  #pragma unroll
  for (int cc = 0; cc < 6; ++cc) *(u16x8*)(arow + cc * 8) = g[cc];
}

// ---------------------------------------------------------------------------
extern "C" void kernel_launch(void* const* d_in, const int* in_sizes, int n_in,
                              void* d_out, int out_size, void* d_ws, size_t ws_size,
                              hipStream_t stream) {
  const float* x      = (const float*)d_in[0];
  const float* qkv_w  = (const float*)d_in[1];
  const float* dw_w   = (const float*)d_in[2];
  const float* proj_w = (const float*)d_in[3];
  const float* temp   = (const float*)d_in[4];

  char* ws = (char*)d_ws;
  unsigned short* xb      = (unsigned short*)(ws);             // 3,145,728
  unsigned short* wqkv    = (unsigned short*)(ws + 3145728);   //   221,184
  float*          qkv_f32 = (float*)(ws + 3440640);            // 18,874,368
  float*          dw_f32  = (float*)(ws + 22315008);           // 18,874,368
  unsigned short* Qr      = (unsigned short*)(ws + 41189376);  //  4,194,304
  unsigned short* Kr      = (unsigned short*)(ws + 45383680);  //  4,194,304
  unsigned short* Vs      = (unsigned short*)(ws + 49577984);  //  3,145,728
  unsigned short* wproj   = (unsigned short*)(ws + 52723712);  //    73,728 (lives to the end)
  // after norm_pack: xb/qkv/dw regions dead -> reuse
  float*          Opart   = (float*)(ws);                      // 25,165,824
  float*          Lpart   = (float*)(ws + 25165824);           //    524,288
  unsigned short* attnb   = (unsigned short*)(ws + 25690112);  //  3,145,728 (< 41,189,376 OK)

  // 0) pack x + weights to bf16
  pack_kernel<<<dim3(136), 256, 0, stream>>>(x, qkv_w, proj_w, xb, wqkv, wproj);
  // 1) qkv 1x1 conv as bf16 MFMA GEMM: [576,192] x [192,4096] per b
  wx_gemm_kernel<8><<<dim3(9, 32, 2), 256, 0, stream>>>(xb, wqkv, qkv_f32, 576);
  // 2) depthwise 3x3 (LDS stencil)
  dw_conv2_kernel<<<dim3(1152), 256, 0, stream>>>(qkv_f32, dw_w, dw_f32);
  // 3) l2norm + temp*log2e + bf16 pack
  norm_pack2_kernel<<<dim3(16, NH, 2), 256, 0, stream>>>(dw_f32, temp, Qr, Kr, Vs);
  // 4) flash attention v3 (static max, KVSPLIT=4)
  flash3_kernel<<<dim3(8, 32, KVSPLIT), 256, 0, stream>>>(Qr, Kr, Vs, temp, Opart, Lpart);
  // 4b) combine splits -> bf16 [px][192]
  combine_kernel<<<dim3(128), 256, 0, stream>>>(Opart, Lpart, attnb);
  // 5) proj 1x1 conv as bf16 MFMA GEMM -> d_out (fp32)
  wx_gemm_kernel<4><<<dim3(3, 64, 2), 256, 0, stream>>>(attnb, wproj, (float*)d_out, 192);
}

// Round 4
// 104.729 us; speedup vs baseline: 3.3779x; 1.3476x over previous
//
#include <hip/hip_runtime.h>
#include <cstdint>
#include <cstddef>

#define HW    4096
#define IMG   64
#define DIMC  192
#define NH    4
#define CH    48
#define CPAD  64
#define KVSPLIT 4
#define NTILE (HW / 64 / KVSPLIT)
#define LOG2E 1.4426950408889634f

typedef __bf16 bf16x8 __attribute__((ext_vector_type(8)));
typedef float  f32x4  __attribute__((ext_vector_type(4)));
typedef unsigned short u16x8 __attribute__((ext_vector_type(8)));

__device__ __forceinline__ unsigned short f2bf(float f) {
  unsigned int u = __builtin_bit_cast(unsigned int, f);
  u = (u + 0x7FFFu + ((u >> 16) & 1u)) >> 16;   // RNE
  return (unsigned short)u;
}
__device__ __forceinline__ float bf2f(unsigned short u) {
  return __builtin_bit_cast(float, (unsigned int)u << 16);
}
__device__ __forceinline__ f32x4 mfma16(bf16x8 a, bf16x8 b, f32x4 c) {
  return __builtin_amdgcn_mfma_f32_16x16x32_bf16(a, b, c, 0, 0, 0);
}
__device__ __forceinline__ void gl16(const void* g, void* l) {
  __builtin_amdgcn_global_load_lds(
      (const __attribute__((address_space(1))) unsigned int*)g,
      (__attribute__((address_space(3))) unsigned int*)l, 16, 0, 0);
}

// ---------------------------------------------------------------------------
// P0: pack to chunk-major bf16.
//   xb:    [b][kc=6][px=4096][32]   (ch = kc*32 + j)
//   wqkv:  [kc=6][oc=576][32]
//   wproj: [kc=6][oc=192][32]
// Grid 67: bx<64 pack x (thread = 1 px, half of channels); bx>=64 weight rows.
// ---------------------------------------------------------------------------
__global__ __launch_bounds__(256) void pack2_kernel(
    const float* __restrict__ x, const float* __restrict__ qkv_w,
    const float* __restrict__ proj_w, unsigned short* __restrict__ xb,
    unsigned short* __restrict__ wqkv, unsigned short* __restrict__ wproj) {
  const int bx = blockIdx.x, tid = threadIdx.x;
  if (bx < 64) {
    const int half = bx & 1;
    const int gpx = (bx >> 1) * 256 + tid;     // 0..8191
    const int b = gpx >> 12, p = gpx & 4095;
    const int ch0 = half * 96;
    const float* src = x + ((size_t)b * DIMC + ch0) * HW + p;
    #pragma unroll
    for (int kc2 = 0; kc2 < 3; ++kc2) {
      const int kc = half * 3 + kc2;
      u16x8 g[4];
      #pragma unroll
      for (int v = 0; v < 4; ++v)
        #pragma unroll
        for (int j = 0; j < 8; ++j)
          g[v][j] = f2bf(src[(size_t)(kc2 * 32 + v * 8 + j) * HW]);
      unsigned short* dst = xb + (((size_t)b * 6 + kc) * HW + p) * 32;
      #pragma unroll
      for (int v = 0; v < 4; ++v) *(u16x8*)(dst + v * 8) = g[v];
    }
  } else {
    const int row = (bx - 64) * 256 + tid;     // 0..767
    if (row < 576) {
      const float* src = qkv_w + (size_t)row * DIMC;
      #pragma unroll
      for (int kc = 0; kc < 6; ++kc) {
        u16x8 g0, g1, g2, g3;
        #pragma unroll
        for (int j = 0; j < 8; ++j) {
          g0[j] = f2bf(src[kc * 32 + j]);      g1[j] = f2bf(src[kc * 32 + 8 + j]);
          g2[j] = f2bf(src[kc * 32 + 16 + j]); g3[j] = f2bf(src[kc * 32 + 24 + j]);
        }
        unsigned short* dst = wqkv + ((size_t)kc * 576 + row) * 32;
        *(u16x8*)dst = g0; *(u16x8*)(dst + 8) = g1;
        *(u16x8*)(dst + 16) = g2; *(u16x8*)(dst + 24) = g3;
      }
    } else {
      const int oc = row - 576;                // 0..191
      const float* src = proj_w + (size_t)oc * DIMC;
      #pragma unroll
      for (int kc = 0; kc < 6; ++kc) {
        u16x8 g0, g1, g2, g3;
        #pragma unroll
        for (int j = 0; j < 8; ++j) {
          g0[j] = f2bf(src[kc * 32 + j]);      g1[j] = f2bf(src[kc * 32 + 8 + j]);
          g2[j] = f2bf(src[kc * 32 + 16 + j]); g3[j] = f2bf(src[kc * 32 + 24 + j]);
        }
        unsigned short* dst = wproj + ((size_t)kc * DIMC + oc) * 32;
        *(u16x8*)dst = g0; *(u16x8*)(dst + 8) = g1;
        *(u16x8*)(dst + 16) = g2; *(u16x8*)(dst + 24) = g3;
      }
    }
  }
}

// ---------------------------------------------------------------------------
// G1: bf16 MFMA GEMM from chunk-major layouts (all loads 1KB/wave coalesced).
// C[b][oc][px] = sum_k W[oc][k] * X[b][px][k]. Wave = 16oc x PF*16 px.
// OBF: write bf16 (u16) else f32. Grid: (OC/64, 4096/(PF*16), B)
// ---------------------------------------------------------------------------
template <int PF, bool OBF>
__global__ __launch_bounds__(256) void wx_gemm2_kernel(
    const unsigned short* __restrict__ xb, const unsigned short* __restrict__ wb,
    void* __restrict__ Cout, int OC) {
  const int tid = threadIdx.x;
  const int lane = tid & 63, wv = tid >> 6;
  const int l15 = lane & 15, l4 = lane >> 4;
  const int oc0 = blockIdx.x * 64 + wv * 16;
  const int px0 = blockIdx.y * (PF * 16);
  const int b   = blockIdx.z;

  f32x4 acc[PF];
  #pragma unroll
  for (int p = 0; p < PF; ++p) acc[p] = f32x4{0.f, 0.f, 0.f, 0.f};

  #pragma unroll
  for (int kc = 0; kc < 6; ++kc) {
    const bf16x8 af = *(const bf16x8*)(wb + ((size_t)kc * OC + oc0 + l15) * 32 + l4 * 8);
    const unsigned short* xrow = xb + (((size_t)b * 6 + kc) * HW + px0 + l15) * 32 + l4 * 8;
    #pragma unroll
    for (int p = 0; p < PF; ++p) {
      const bf16x8 bf = *(const bf16x8*)(xrow + p * 512);
      acc[p] = mfma16(af, bf, acc[p]);
    }
  }
  if (OBF) {
    unsigned short* Cb = (unsigned short*)Cout + ((size_t)b * OC + oc0) * HW + px0;
    #pragma unroll
    for (int p = 0; p < PF; ++p)
      #pragma unroll
      for (int r = 0; r < 4; ++r)
        Cb[(size_t)(l4 * 4 + r) * HW + p * 16 + l15] = f2bf(acc[p][r]);
  } else {
    float* Cb = (float*)Cout + ((size_t)b * OC + oc0) * HW + px0;
    #pragma unroll
    for (int p = 0; p < PF; ++p)
      #pragma unroll
      for (int r = 0; r < 4; ++r)
        Cb[(size_t)(l4 * 4 + r) * HW + p * 16 + l15] = acc[p][r];
  }
}

// ---------------------------------------------------------------------------
// K2: depthwise 3x3, bf16 in/out, fp32 LDS tile + rolling registers.
// ---------------------------------------------------------------------------
__global__ __launch_bounds__(256) void dw_conv3_kernel(
    const unsigned short* __restrict__ X, const float* __restrict__ W,
    unsigned short* __restrict__ Y) {
  __shared__ float T[66][72];
  const int bc = blockIdx.x;            // b*576 + ch
  const int ch = bc % 576;
  const int tid = threadIdx.x;
  const unsigned short* Xb = X + (size_t)bc * HW;
  #pragma unroll
  for (int i = 0; i < 4; ++i) {
    const int idx = i * 256 + tid;      // quads
    const int row = idx >> 4, c4 = (idx & 15) << 2;
    const ushort4 u = *(const ushort4*)(Xb + row * 64 + c4);
    float4 f; f.x = bf2f(u.x); f.y = bf2f(u.y); f.z = bf2f(u.z); f.w = bf2f(u.w);
    *(float4*)&T[row + 1][c4 + 4] = f;
  }
  if (tid < 72) { T[0][tid] = 0.f; T[65][tid] = 0.f; }
  if (tid >= 128 && tid < 194) { const int r = tid - 128; T[r][3] = 0.f; T[r][68] = 0.f; }
  float w[9];
  #pragma unroll
  for (int i = 0; i < 9; ++i) w[i] = W[ch * 9 + i];
  __syncthreads();

  const int xx = tid & 63, ys = (tid >> 6) << 4;
  const int c = xx + 4;
  float a0 = T[ys][c - 1],     a1 = T[ys][c],     a2 = T[ys][c + 1];
  float b0 = T[ys + 1][c - 1], b1 = T[ys + 1][c], b2 = T[ys + 1][c + 1];
  unsigned short* Yb = Y + (size_t)bc * HW;
  #pragma unroll
  for (int k = 0; k < 16; ++k) {
    const float c0 = T[ys + k + 2][c - 1], c1 = T[ys + k + 2][c], c2 = T[ys + k + 2][c + 1];
    const float s = w[0] * a0 + w[1] * a1 + w[2] * a2
                  + w[3] * b0 + w[4] * b1 + w[5] * b2
                  + w[6] * c0 + w[7] * c1 + w[8] * c2;
    Yb[(ys + k) * 64 + xx] = f2bf(s);
    a0 = b0; a1 = b1; a2 = b2; b0 = c0; b1 = c1; b2 = c2;
  }
}

// ---------------------------------------------------------------------------
// K3: l2norm + temp*log2e + pack (bf16 input), split by q/k/v section.
// Grid: (16, 12 = sel*4+h, 2). Layouts unchanged:
//   Qr: [bh][p][64] linear; Kr: granule g at g^KSWZ(p); Vs: k at k^((c&7)<<3)
// ---------------------------------------------------------------------------
__global__ __launch_bounds__(256) void norm_pack3_kernel(
    const unsigned short* __restrict__ Dw, const float* __restrict__ temp,
    unsigned short* __restrict__ Qr, unsigned short* __restrict__ Kr,
    unsigned short* __restrict__ Vs) {
  const int px = blockIdx.x * 256 + threadIdx.x;
  const int sel = blockIdx.y >> 2, h = blockIdx.y & 3;
  const int b = blockIdx.z;
  const int bh = b * NH + h;
  const unsigned short* base = Dw + ((size_t)b * 576 + sel * DIMC + h * CH) * HW + px;

  float v[CH];
  if (sel == 2) {  // V: no norm
    const int kt = px & ~63, kl = px & 63;
    #pragma unroll
    for (int c = 0; c < CH; ++c)
      Vs[((size_t)bh * CH + c) * HW + kt + (kl ^ ((c & 7) << 3))] = base[(size_t)c * HW];
    return;
  }
  float ss = 0.f;
  #pragma unroll
  for (int j = 0; j < CH; ++j) { v[j] = bf2f(base[(size_t)j * HW]); ss += v[j] * v[j]; }
  const u16x8 zz = {0, 0, 0, 0, 0, 0, 0, 0};
  if (sel == 0) {  // Q: fold temperature*log2e
    const float sc = temp[h] * LOG2E / fmaxf(sqrtf(ss), 1e-12f);
    u16x8 gr[8];
    #pragma unroll
    for (int g = 0; g < 6; ++g)
      #pragma unroll
      for (int j = 0; j < 8; ++j) gr[g][j] = f2bf(v[g * 8 + j] * sc);
    gr[6] = zz; gr[7] = zz;
    unsigned short* qrow = Qr + ((size_t)bh * HW + px) * CPAD;
    #pragma unroll
    for (int g = 0; g < 8; ++g) *(u16x8*)(qrow + g * 8) = gr[g];
  } else {         // K: swizzled granules
    const int ksw = (px & 3) | (((px >> 3) & 1) << 2);
    const float sc = 1.0f / fmaxf(sqrtf(ss), 1e-12f);
    u16x8 gr[8];
    #pragma unroll
    for (int g = 0; g < 6; ++g)
      #pragma unroll
      for (int j = 0; j < 8; ++j) gr[g][j] = f2bf(v[g * 8 + j] * sc);
    gr[6] = zz; gr[7] = zz;
    unsigned short* krow = Kr + ((size_t)bh * HW + px) * CPAD;
    #pragma unroll
    for (int g = 0; g < 8; ++g) *(u16x8*)(krow + (g ^ ksw) * 8) = gr[g];
  }
}

// ---------------------------------------------------------------------------
// K4: flash attention v4. Static softmax bound in C-init, KVSPLIT=4,
// bf16 Opart epilogue, pointer-increment staging.
// ---------------------------------------------------------------------------
__global__ __launch_bounds__(256, 4) void flash4_kernel(
    const unsigned short* __restrict__ Qr,
    const unsigned short* __restrict__ Kr,
    const unsigned short* __restrict__ Vs,
    const float* __restrict__ temp,
    unsigned short* __restrict__ Opart, float* __restrict__ Lpart) {
  __shared__ __align__(16) unsigned short Kl[2][64 * 64];   // 2 x 8KB
  __shared__ __align__(16) unsigned short Vl[2][48 * 64];   // 2 x 6KB
  const int tid = threadIdx.x;
  const int lane = tid & 63, wv = tid >> 6;
  const int l15 = lane & 15, l4 = lane >> 4;
  const int bh = blockIdx.x, qt = blockIdx.y, sp = blockIdx.z;
  const int qb = qt * 128 + wv * 32;
  const float m = fabsf(temp[bh & 3]) * LOG2E * 1.05f + 0.1f;

  const unsigned short* Qb = Qr + ((size_t)bh * HW + qb) * CPAD;
  bf16x8 qf[2][2];
  #pragma unroll
  for (int qg = 0; qg < 2; ++qg)
    #pragma unroll
    for (int hh = 0; hh < 2; ++hh)
      qf[qg][hh] = *(const bf16x8*)(Qb + (size_t)(qg * 16 + l15) * CPAD + hh * 32 + l4 * 8);

  // staging pointers (advance by constants per tile)
  const char* kg = (const char*)Kr + ((size_t)bh * HW + (size_t)sp * (HW / KVSPLIT)) * 128;
  const char* vg = (const char*)Vs + (size_t)bh * CH * HW * 2 + (size_t)sp * (HW / KVSPLIT) * 2;
  const int koA = tid * 16;
  const int vgA = (tid >> 3) * 8192 + (tid & 7) * 16;
  const int vgB = (32 + (tid >> 3)) * 8192 + (tid & 7) * 16;

  auto stage = [&](int buf, const char* kp, const char* vp) {
    char* kl = (char*)&Kl[buf][0];
    gl16(kp + koA,        kl + koA);
    gl16(kp + 4096 + koA, kl + 4096 + koA);
    char* vl = (char*)&Vl[buf][0];
    gl16(vp + vgA, vl + tid * 16);
    if (tid < 128) gl16(vp + vgB, vl + 4096 + tid * 16);
  };

  f32x4 o[3][2];
  #pragma unroll
  for (int cg = 0; cg < 3; ++cg)
    #pragma unroll
    for (int qg = 0; qg < 2; ++qg) o[cg][qg] = f32x4{0.f, 0.f, 0.f, 0.f};
  float l[2] = {0.f, 0.f};
  const f32x4 zinit = {-m, -m, -m, -m};

  stage(0, kg, vg);
  kg += 8192; vg += 128;
  __syncthreads();
  int cur = 0;
  for (int t = 0; t < NTILE; ++t) {
    if (t + 1 < NTILE) { stage(cur ^ 1, kg, vg); kg += 8192; vg += 128; }
    const char* KL = (const char*)&Kl[cur][0];
    const char* VL = (const char*)&Vl[cur][0];

    // ---- S^T - m = K*Q + (-m) ----
    f32x4 s[2][4];
    __builtin_amdgcn_s_setprio(1);
    #pragma unroll
    for (int n = 0; n < 4; ++n) {
      const int row = (n >> 1) * 32 + (l15 >> 2) * 8 + (n & 1) * 4 + (l15 & 3);
      const int sw = (l15 & 7) << 4;
      const bf16x8 kf0 = *(const bf16x8*)(KL + row * 128 + ((l4 << 4) ^ sw));
      const bf16x8 kf1 = *(const bf16x8*)(KL + row * 128 + (((4 + l4) << 4) ^ sw));
      #pragma unroll
      for (int qg = 0; qg < 2; ++qg) {
        f32x4 z = mfma16(kf0, qf[qg][0], zinit);
        s[qg][n] = mfma16(kf1, qf[qg][1], z);
      }
    }
    __builtin_amdgcn_s_setprio(0);

    // ---- p = exp2(s), row-sum ----
    #pragma unroll
    for (int qg = 0; qg < 2; ++qg) {
      float a[16];
      #pragma unroll
      for (int n = 0; n < 4; ++n)
        #pragma unroll
        for (int r = 0; r < 4; ++r) {
          const float p = exp2f(s[qg][n][r]);
          s[qg][n][r] = p;
          a[n * 4 + r] = p;
        }
      #pragma unroll
      for (int i = 0; i < 8; ++i) a[i] += a[i + 8];
      #pragma unroll
      for (int i = 0; i < 4; ++i) a[i] += a[i + 4];
      float sum = (a[0] + a[1]) + (a[2] + a[3]);
      sum += __shfl_xor(sum, 16);
      sum += __shfl_xor(sum, 32);
      l[qg] += sum;
    }

    // ---- O^T += V^T * P^T ----
    #pragma unroll
    for (int kc = 0; kc < 2; ++kc) {
      bf16x8 pb[2];
      #pragma unroll
      for (int qg = 0; qg < 2; ++qg)
        #pragma unroll
        for (int j = 0; j < 8; ++j)
          pb[qg][j] = (__bf16)s[qg][kc * 2 + (j >> 2)][j & 3];
      __builtin_amdgcn_s_setprio(1);
      #pragma unroll
      for (int cg = 0; cg < 3; ++cg) {
        const int vrow = cg * 16 + l15;
        const bf16x8 vf = *(const bf16x8*)(VL + vrow * 128 + (((kc * 4 + l4) ^ (l15 & 7)) << 4));
        #pragma unroll
        for (int qg = 0; qg < 2; ++qg) o[cg][qg] = mfma16(vf, pb[qg], o[cg][qg]);
      }
      __builtin_amdgcn_s_setprio(0);
    }
    __syncthreads();
    cur ^= 1;
  }

  unsigned short* Ob = Opart + (size_t)(sp * 8 + bh) * CH * HW;
  #pragma unroll
  for (int cg = 0; cg < 3; ++cg)
    #pragma unroll
    for (int qg = 0; qg < 2; ++qg)
      #pragma unroll
      for (int r = 0; r < 4; ++r)
        Ob[(size_t)(cg * 16 + l4 * 4 + r) * HW + qb + qg * 16 + l15] = f2bf(o[cg][qg][r]);
  if (l4 == 0) {
    #pragma unroll
    for (int qg = 0; qg < 2; ++qg)
      Lpart[(size_t)(sp * 8 + bh) * HW + qb + qg * 16 + l15] = l[qg];
  }
}

// ---------------------------------------------------------------------------
// K4b: combine splits -> attnb chunk-major [b][kc=6][px][32]
// ---------------------------------------------------------------------------
__global__ __launch_bounds__(256) void combine2_kernel(
    const unsigned short* __restrict__ Opart, const float* __restrict__ Lpart,
    unsigned short* __restrict__ attnb) {
  const int idx = blockIdx.x * 256 + threadIdx.x;   // bh*4096 + q
  const int bh = idx >> 12, q = idx & 4095;
  float lsum = 0.f;
  #pragma unroll
  for (int sp = 0; sp < KVSPLIT; ++sp) lsum += Lpart[(size_t)(sp * 8 + bh) * HW + q];
  const float inv = 1.f / lsum;
  const int b = bh >> 2, h = bh & 3;
  float v[CH];
  #pragma unroll
  for (int c = 0; c < CH; ++c) {
    float s = 0.f;
    #pragma unroll
    for (int sp = 0; sp < KVSPLIT; ++sp)
      s += bf2f(Opart[((size_t)(sp * 8 + bh) * CH + c) * HW + q]);
    v[c] = s * inv;
  }
  // write 3 x 16-channel runs (16-aligned within 32-chunks)
  #pragma unroll
  for (int cc = 0; cc < 3; ++cc) {
    const int ch0 = h * CH + cc * 16;
    const int kc = ch0 >> 5, off = ch0 & 31;
    unsigned short* dst = attnb + (((size_t)b * 6 + kc) * HW + q) * 32 + off;
    u16x8 g0, g1;
    #pragma unroll
    for (int j = 0; j < 8; ++j) {
      g0[j] = f2bf(v[cc * 16 + j]);
      g1[j] = f2bf(v[cc * 16 + 8 + j]);
    }
    *(u16x8*)dst = g0;
    *(u16x8*)(dst + 8) = g1;
  }
}

// ---------------------------------------------------------------------------
extern "C" void kernel_launch(void* const* d_in, const int* in_sizes, int n_in,
                              void* d_out, int out_size, void* d_ws, size_t ws_size,
                              hipStream_t stream) {
  const float* x      = (const float*)d_in[0];
  const float* qkv_w  = (const float*)d_in[1];
  const float* dw_w   = (const float*)d_in[2];
  const float* proj_w = (const float*)d_in[3];
  const float* temp   = (const float*)d_in[4];

  char* ws = (char*)d_ws;
  unsigned short* xb    = (unsigned short*)(ws);              //  3,145,728
  unsigned short* wqkv  = (unsigned short*)(ws + 3145728);    //    221,184
  unsigned short* wproj = (unsigned short*)(ws + 3366912);    //     73,728
  unsigned short* qkvb  = (unsigned short*)(ws + 3440640);    //  9,437,184
  unsigned short* dwb   = (unsigned short*)(ws + 12877824);   //  9,437,184
  unsigned short* Qr    = (unsigned short*)(ws + 22315008);   //  4,194,304
  unsigned short* Kr    = (unsigned short*)(ws + 26509312);   //  4,194,304
  unsigned short* Vs    = (unsigned short*)(ws + 30703616);   //  3,145,728
  unsigned short* Opart = (unsigned short*)(ws + 33849344);   // 12,582,912
  float*          Lpart = (float*)(ws + 46432256);            //    524,288
  unsigned short* attnb = (unsigned short*)(ws + 46956544);   //  3,145,728

  // 0) pack x + weights to chunk-major bf16
  pack2_kernel<<<dim3(67), 256, 0, stream>>>(x, qkv_w, proj_w, xb, wqkv, wproj);
  // 1) qkv 1x1 conv (bf16 MFMA GEMM, bf16 out)
  wx_gemm2_kernel<8, true><<<dim3(9, 32, 2), 256, 0, stream>>>(xb, wqkv, qkvb, 576);
  // 2) depthwise 3x3 (bf16 in/out)
  dw_conv3_kernel<<<dim3(1152), 256, 0, stream>>>(qkvb, dw_w, dwb);
  // 3) l2norm + temp*log2e + pack (section-split grid)
  norm_pack3_kernel<<<dim3(16, 12, 2), 256, 0, stream>>>(dwb, temp, Qr, Kr, Vs);
  // 4) flash attention v4 (static max, KVSPLIT=4, bf16 Opart)
  flash4_kernel<<<dim3(8, 32, KVSPLIT), 256, 0, stream>>>(Qr, Kr, Vs, temp, Opart, Lpart);
  // 4b) combine -> chunk-major attnb
  combine2_kernel<<<dim3(128), 256, 0, stream>>>(Opart, Lpart, attnb);
  // 5) proj 1x1 conv -> d_out (fp32)
  wx_gemm2_kernel<4, false><<<dim3(3, 64, 2), 256, 0, stream>>>(attnb, wproj, (float*)d_out, 192);
}

// Round 5
// 84.970 us; speedup vs baseline: 4.1634x; 1.2325x over previous
//
#include <hip/hip_runtime.h>
#include <cstdint>
#include <cstddef>

#define HW    4096
#define IMG   64
#define DIMC  192
#define NH    4
#define CH    48
#define CPAD  64
#define KVSPLIT 4
#define NTILE (HW / 64 / KVSPLIT)
#define LOG2E 1.4426950408889634f

typedef __bf16 bf16x8 __attribute__((ext_vector_type(8)));
typedef float  f32x4  __attribute__((ext_vector_type(4)));
typedef unsigned short u16x8 __attribute__((ext_vector_type(8)));

#if __has_builtin(__builtin_amdgcn_exp2f)
#define EXP2(x) __builtin_amdgcn_exp2f(x)
#else
#define EXP2(x) exp2f(x)
#endif

__device__ __forceinline__ unsigned short f2bf(float f) {
  unsigned int u = __builtin_bit_cast(unsigned int, f);
  u = (u + 0x7FFFu + ((u >> 16) & 1u)) >> 16;   // RNE
  return (unsigned short)u;
}
__device__ __forceinline__ float bf2f(unsigned short u) {
  return __builtin_bit_cast(float, (unsigned int)u << 16);
}
__device__ __forceinline__ f32x4 mfma16(bf16x8 a, bf16x8 b, f32x4 c) {
  return __builtin_amdgcn_mfma_f32_16x16x32_bf16(a, b, c, 0, 0, 0);
}
__device__ __forceinline__ void gl16(const void* g, void* l) {
  __builtin_amdgcn_global_load_lds(
      (const __attribute__((address_space(1))) unsigned int*)g,
      (__attribute__((address_space(3))) unsigned int*)l, 16, 0, 0);
}

// ---------------------------------------------------------------------------
// P0: pack to chunk-major bf16.
//   xb:    [b][kc=6][px=4096][32]   (ch = kc*32 + j)
//   wqkv:  [kc=6][oc=576][32]
//   wproj: [kc=6][oc=192][32]
// ---------------------------------------------------------------------------
__global__ __launch_bounds__(256) void pack2_kernel(
    const float* __restrict__ x, const float* __restrict__ qkv_w,
    const float* __restrict__ proj_w, unsigned short* __restrict__ xb,
    unsigned short* __restrict__ wqkv, unsigned short* __restrict__ wproj) {
  const int bx = blockIdx.x, tid = threadIdx.x;
  if (bx < 64) {
    const int half = bx & 1;
    const int gpx = (bx >> 1) * 256 + tid;     // 0..8191
    const int b = gpx >> 12, p = gpx & 4095;
    const int ch0 = half * 96;
    const float* src = x + ((size_t)b * DIMC + ch0) * HW + p;
    #pragma unroll
    for (int kc2 = 0; kc2 < 3; ++kc2) {
      const int kc = half * 3 + kc2;
      u16x8 g[4];
      #pragma unroll
      for (int v = 0; v < 4; ++v)
        #pragma unroll
        for (int j = 0; j < 8; ++j)
          g[v][j] = f2bf(src[(size_t)(kc2 * 32 + v * 8 + j) * HW]);
      unsigned short* dst = xb + (((size_t)b * 6 + kc) * HW + p) * 32;
      #pragma unroll
      for (int v = 0; v < 4; ++v) *(u16x8*)(dst + v * 8) = g[v];
    }
  } else {
    const int row = (bx - 64) * 256 + tid;     // 0..767
    if (row < 576) {
      const float* src = qkv_w + (size_t)row * DIMC;
      #pragma unroll
      for (int kc = 0; kc < 6; ++kc) {
        u16x8 g0, g1, g2, g3;
        #pragma unroll
        for (int j = 0; j < 8; ++j) {
          g0[j] = f2bf(src[kc * 32 + j]);      g1[j] = f2bf(src[kc * 32 + 8 + j]);
          g2[j] = f2bf(src[kc * 32 + 16 + j]); g3[j] = f2bf(src[kc * 32 + 24 + j]);
        }
        unsigned short* dst = wqkv + ((size_t)kc * 576 + row) * 32;
        *(u16x8*)dst = g0; *(u16x8*)(dst + 8) = g1;
        *(u16x8*)(dst + 16) = g2; *(u16x8*)(dst + 24) = g3;
      }
    } else {
      const int oc = row - 576;                // 0..191
      const float* src = proj_w + (size_t)oc * DIMC;
      #pragma unroll
      for (int kc = 0; kc < 6; ++kc) {
        u16x8 g0, g1, g2, g3;
        #pragma unroll
        for (int j = 0; j < 8; ++j) {
          g0[j] = f2bf(src[kc * 32 + j]);      g1[j] = f2bf(src[kc * 32 + 8 + j]);
          g2[j] = f2bf(src[kc * 32 + 16 + j]); g3[j] = f2bf(src[kc * 32 + 24 + j]);
        }
        unsigned short* dst = wproj + ((size_t)kc * DIMC + oc) * 32;
        *(u16x8*)dst = g0; *(u16x8*)(dst + 8) = g1;
        *(u16x8*)(dst + 16) = g2; *(u16x8*)(dst + 24) = g3;
      }
    }
  }
}

// ---------------------------------------------------------------------------
// G1: bf16 MFMA GEMM from chunk-major layouts (all loads 1KB/wave coalesced).
// ---------------------------------------------------------------------------
template <int PF, bool OBF>
__global__ __launch_bounds__(256) void wx_gemm2_kernel(
    const unsigned short* __restrict__ xb, const unsigned short* __restrict__ wb,
    void* __restrict__ Cout, int OC) {
  const int tid = threadIdx.x;
  const int lane = tid & 63, wv = tid >> 6;
  const int l15 = lane & 15, l4 = lane >> 4;
  const int oc0 = blockIdx.x * 64 + wv * 16;
  const int px0 = blockIdx.y * (PF * 16);
  const int b   = blockIdx.z;

  f32x4 acc[PF];
  #pragma unroll
  for (int p = 0; p < PF; ++p) acc[p] = f32x4{0.f, 0.f, 0.f, 0.f};

  #pragma unroll
  for (int kc = 0; kc < 6; ++kc) {
    const bf16x8 af = *(const bf16x8*)(wb + ((size_t)kc * OC + oc0 + l15) * 32 + l4 * 8);
    const unsigned short* xrow = xb + (((size_t)b * 6 + kc) * HW + px0 + l15) * 32 + l4 * 8;
    #pragma unroll
    for (int p = 0; p < PF; ++p) {
      const bf16x8 bf = *(const bf16x8*)(xrow + p * 512);
      acc[p] = mfma16(af, bf, acc[p]);
    }
  }
  if (OBF) {
    unsigned short* Cb = (unsigned short*)Cout + ((size_t)b * OC + oc0) * HW + px0;
    #pragma unroll
    for (int p = 0; p < PF; ++p)
      #pragma unroll
      for (int r = 0; r < 4; ++r)
        Cb[(size_t)(l4 * 4 + r) * HW + p * 16 + l15] = f2bf(acc[p][r]);
  } else {
    float* Cb = (float*)Cout + ((size_t)b * OC + oc0) * HW + px0;
    #pragma unroll
    for (int p = 0; p < PF; ++p)
      #pragma unroll
      for (int r = 0; r < 4; ++r)
        Cb[(size_t)(l4 * 4 + r) * HW + p * 16 + l15] = acc[p][r];
  }
}

// ---------------------------------------------------------------------------
// K2: depthwise 3x3, bf16 in/out, fp32 LDS tile + rolling registers.
// ---------------------------------------------------------------------------
__global__ __launch_bounds__(256) void dw_conv3_kernel(
    const unsigned short* __restrict__ X, const float* __restrict__ W,
    unsigned short* __restrict__ Y) {
  __shared__ float T[66][72];
  const int bc = blockIdx.x;            // b*576 + ch
  const int ch = bc % 576;
  const int tid = threadIdx.x;
  const unsigned short* Xb = X + (size_t)bc * HW;
  #pragma unroll
  for (int i = 0; i < 4; ++i) {
    const int idx = i * 256 + tid;      // quads
    const int row = idx >> 4, c4 = (idx & 15) << 2;
    const ushort4 u = *(const ushort4*)(Xb + row * 64 + c4);
    float4 f; f.x = bf2f(u.x); f.y = bf2f(u.y); f.z = bf2f(u.z); f.w = bf2f(u.w);
    *(float4*)&T[row + 1][c4 + 4] = f;
  }
  if (tid < 72) { T[0][tid] = 0.f; T[65][tid] = 0.f; }
  if (tid >= 128 && tid < 194) { const int r = tid - 128; T[r][3] = 0.f; T[r][68] = 0.f; }
  float w[9];
  #pragma unroll
  for (int i = 0; i < 9; ++i) w[i] = W[ch * 9 + i];
  __syncthreads();

  const int xx = tid & 63, ys = (tid >> 6) << 4;
  const int c = xx + 4;
  float a0 = T[ys][c - 1],     a1 = T[ys][c],     a2 = T[ys][c + 1];
  float b0 = T[ys + 1][c - 1], b1 = T[ys + 1][c], b2 = T[ys + 1][c + 1];
  unsigned short* Yb = Y + (size_t)bc * HW;
  #pragma unroll
  for (int k = 0; k < 16; ++k) {
    const float c0 = T[ys + k + 2][c - 1], c1 = T[ys + k + 2][c], c2 = T[ys + k + 2][c + 1];
    const float s = w[0] * a0 + w[1] * a1 + w[2] * a2
                  + w[3] * b0 + w[4] * b1 + w[5] * b2
                  + w[6] * c0 + w[7] * c1 + w[8] * c2;
    Yb[(ys + k) * 64 + xx] = f2bf(s);
    a0 = b0; a1 = b1; a2 = b2; b0 = c0; b1 = c1; b2 = c2;
  }
}

// ---------------------------------------------------------------------------
// K3: l2norm + temp*log2e + pack (bf16 input), split by q/k/v section.
// Grid: (16, 12 = sel*4+h, 2).
//   Qr: [bh][p][64] linear; Kr: granule g at g^KSWZ(p); Vs: k at k^((c&7)<<3)
// ---------------------------------------------------------------------------
__global__ __launch_bounds__(256) void norm_pack3_kernel(
    const unsigned short* __restrict__ Dw, const float* __restrict__ temp,
    unsigned short* __restrict__ Qr, unsigned short* __restrict__ Kr,
    unsigned short* __restrict__ Vs) {
  const int px = blockIdx.x * 256 + threadIdx.x;
  const int sel = blockIdx.y >> 2, h = blockIdx.y & 3;
  const int b = blockIdx.z;
  const int bh = b * NH + h;
  const unsigned short* base = Dw + ((size_t)b * 576 + sel * DIMC + h * CH) * HW + px;

  float v[CH];
  if (sel == 2) {  // V: no norm
    const int kt = px & ~63, kl = px & 63;
    #pragma unroll
    for (int c = 0; c < CH; ++c)
      Vs[((size_t)bh * CH + c) * HW + kt + (kl ^ ((c & 7) << 3))] = base[(size_t)c * HW];
    return;
  }
  float ss = 0.f;
  #pragma unroll
  for (int j = 0; j < CH; ++j) { v[j] = bf2f(base[(size_t)j * HW]); ss += v[j] * v[j]; }
  const u16x8 zz = {0, 0, 0, 0, 0, 0, 0, 0};
  if (sel == 0) {  // Q: fold temperature*log2e
    const float sc = temp[h] * LOG2E / fmaxf(sqrtf(ss), 1e-12f);
    u16x8 gr[8];
    #pragma unroll
    for (int g = 0; g < 6; ++g)
      #pragma unroll
      for (int j = 0; j < 8; ++j) gr[g][j] = f2bf(v[g * 8 + j] * sc);
    gr[6] = zz; gr[7] = zz;
    unsigned short* qrow = Qr + ((size_t)bh * HW + px) * CPAD;
    #pragma unroll
    for (int g = 0; g < 8; ++g) *(u16x8*)(qrow + g * 8) = gr[g];
  } else {         // K: swizzled granules
    const int ksw = (px & 3) | (((px >> 3) & 1) << 2);
    const float sc = 1.0f / fmaxf(sqrtf(ss), 1e-12f);
    u16x8 gr[8];
    #pragma unroll
    for (int g = 0; g < 6; ++g)
      #pragma unroll
      for (int j = 0; j < 8; ++j) gr[g][j] = f2bf(v[g * 8 + j] * sc);
    gr[6] = zz; gr[7] = zz;
    unsigned short* krow = Kr + ((size_t)bh * HW + px) * CPAD;
    #pragma unroll
    for (int g = 0; g < 8; ++g) *(u16x8*)(krow + (g ^ ksw) * 8) = gr[g];
  }
}

// ---------------------------------------------------------------------------
// K4: flash attention v5.
//  - static softmax bound in C-init (no max tracking)
//  - exp2 via raw v_exp_f32 builtin (args bounded, no denormal risk)
//  - row-sum l computed by MFMA ones-channel (V LDS rows 48..63: ones+zeros,
//    written once in prologue) -> no per-tile sum tree, no shuffles
// ---------------------------------------------------------------------------
__global__ __launch_bounds__(256, 4) void flash5_kernel(
    const unsigned short* __restrict__ Qr,
    const unsigned short* __restrict__ Kr,
    const unsigned short* __restrict__ Vs,
    const float* __restrict__ temp,
    unsigned short* __restrict__ Opart, float* __restrict__ Lpart) {
  __shared__ __align__(16) unsigned short Kl[2][64 * 64];   // 2 x 8KB
  __shared__ __align__(16) unsigned short Vl[2][64 * 64];   // 2 x 8KB (rows 48+: const)
  const int tid = threadIdx.x;
  const int lane = tid & 63, wv = tid >> 6;
  const int l15 = lane & 15, l4 = lane >> 4;
  const int bh = blockIdx.x, qt = blockIdx.y, sp = blockIdx.z;
  const int qb = qt * 128 + wv * 32;
  const float m = fabsf(temp[bh & 3]) * LOG2E * 1.05f + 0.1f;

  // constant rows 48..63 of V: row 48 = ones (P row-sum channel), rest zero
  for (int i = tid; i < 1024; i += 256) {
    const unsigned short vv = (i < 64) ? (unsigned short)0x3F80 : (unsigned short)0;
    Vl[0][3072 + i] = vv;
    Vl[1][3072 + i] = vv;
  }

  const unsigned short* Qb = Qr + ((size_t)bh * HW + qb) * CPAD;
  bf16x8 qf[2][2];
  #pragma unroll
  for (int qg = 0; qg < 2; ++qg)
    #pragma unroll
    for (int hh = 0; hh < 2; ++hh)
      qf[qg][hh] = *(const bf16x8*)(Qb + (size_t)(qg * 16 + l15) * CPAD + hh * 32 + l4 * 8);

  const char* kg = (const char*)Kr + ((size_t)bh * HW + (size_t)sp * (HW / KVSPLIT)) * 128;
  const char* vg = (const char*)Vs + (size_t)bh * CH * HW * 2 + (size_t)sp * (HW / KVSPLIT) * 2;
  const int koA = tid * 16;
  const int vgA = (tid >> 3) * 8192 + (tid & 7) * 16;
  const int vgB = (32 + (tid >> 3)) * 8192 + (tid & 7) * 16;

  auto stage = [&](int buf, const char* kp, const char* vp) {
    char* kl = (char*)&Kl[buf][0];
    gl16(kp + koA,        kl + koA);
    gl16(kp + 4096 + koA, kl + 4096 + koA);
    char* vl = (char*)&Vl[buf][0];
    gl16(vp + vgA, vl + tid * 16);
    if (tid < 128) gl16(vp + vgB, vl + 4096 + tid * 16);
  };

  f32x4 o[4][2];
  #pragma unroll
  for (int cg = 0; cg < 4; ++cg)
    #pragma unroll
    for (int qg = 0; qg < 2; ++qg) o[cg][qg] = f32x4{0.f, 0.f, 0.f, 0.f};
  const f32x4 zinit = {-m, -m, -m, -m};

  stage(0, kg, vg);
  kg += 8192; vg += 128;
  __syncthreads();
  int cur = 0;
  for (int t = 0; t < NTILE; ++t) {
    if (t + 1 < NTILE) { stage(cur ^ 1, kg, vg); kg += 8192; vg += 128; }
    const char* KL = (const char*)&Kl[cur][0];
    const char* VL = (const char*)&Vl[cur][0];

    // ---- S^T - m = K*Q + (-m) ----
    f32x4 s[2][4];
    __builtin_amdgcn_s_setprio(1);
    #pragma unroll
    for (int n = 0; n < 4; ++n) {
      const int row = (n >> 1) * 32 + (l15 >> 2) * 8 + (n & 1) * 4 + (l15 & 3);
      const int sw = (l15 & 7) << 4;
      const bf16x8 kf0 = *(const bf16x8*)(KL + row * 128 + ((l4 << 4) ^ sw));
      const bf16x8 kf1 = *(const bf16x8*)(KL + row * 128 + (((4 + l4) << 4) ^ sw));
      #pragma unroll
      for (int qg = 0; qg < 2; ++qg) {
        f32x4 z = mfma16(kf0, qf[qg][0], zinit);
        s[qg][n] = mfma16(kf1, qf[qg][1], z);
      }
    }
    __builtin_amdgcn_s_setprio(0);

    // ---- p = exp2(s) (single v_exp_f32 each; no sum tree) ----
    #pragma unroll
    for (int qg = 0; qg < 2; ++qg)
      #pragma unroll
      for (int n = 0; n < 4; ++n)
        #pragma unroll
        for (int r = 0; r < 4; ++r)
          s[qg][n][r] = EXP2(s[qg][n][r]);

    // ---- O^T += V^T * P^T (cg=3 is the ones-channel -> row sums) ----
    #pragma unroll
    for (int kc = 0; kc < 2; ++kc) {
      bf16x8 pb[2];
      #pragma unroll
      for (int qg = 0; qg < 2; ++qg)
        #pragma unroll
        for (int j = 0; j < 8; ++j)
          pb[qg][j] = (__bf16)s[qg][kc * 2 + (j >> 2)][j & 3];
      __builtin_amdgcn_s_setprio(1);
      #pragma unroll
      for (int cg = 0; cg < 4; ++cg) {
        const int vrow = cg * 16 + l15;
        const bf16x8 vf = *(const bf16x8*)(VL + vrow * 128 + (((kc * 4 + l4) ^ (l15 & 7)) << 4));
        #pragma unroll
        for (int qg = 0; qg < 2; ++qg) o[cg][qg] = mfma16(vf, pb[qg], o[cg][qg]);
      }
      __builtin_amdgcn_s_setprio(0);
    }
    __syncthreads();
    cur ^= 1;
  }

  unsigned short* Ob = Opart + (size_t)(sp * 8 + bh) * CH * HW;
  #pragma unroll
  for (int cg = 0; cg < 3; ++cg)
    #pragma unroll
    for (int qg = 0; qg < 2; ++qg)
      #pragma unroll
      for (int r = 0; r < 4; ++r)
        Ob[(size_t)(cg * 16 + l4 * 4 + r) * HW + qb + qg * 16 + l15] = f2bf(o[cg][qg][r]);
  if (l4 == 0) {
    #pragma unroll
    for (int qg = 0; qg < 2; ++qg)
      Lpart[(size_t)(sp * 8 + bh) * HW + qb + qg * 16 + l15] = o[3][qg][0];
  }
}

// ---------------------------------------------------------------------------
// K4b: combine splits -> attnb chunk-major [b][kc=6][px][32]
// Grid 256 blocks: block = (bh, 128-px group); thread = (c-half, px)
// ---------------------------------------------------------------------------
__global__ __launch_bounds__(256) void combine3_kernel(
    const unsigned short* __restrict__ Opart, const float* __restrict__ Lpart,
    unsigned short* __restrict__ attnb) {
  const int tid = threadIdx.x;
  const int bh = blockIdx.x >> 5;
  const int q  = ((blockIdx.x & 31) << 7) + (tid & 127);
  const int half = tid >> 7;
  float lsum = 0.f;
  #pragma unroll
  for (int sp = 0; sp < KVSPLIT; ++sp) lsum += Lpart[(size_t)(sp * 8 + bh) * HW + q];
  const float inv = 1.f / lsum;
  const int b = bh >> 2, h = bh & 3;
  const int c0 = half * 24;
  float v[24];
  #pragma unroll
  for (int c = 0; c < 24; ++c) {
    float s = 0.f;
    #pragma unroll
    for (int sp = 0; sp < KVSPLIT; ++sp)
      s += bf2f(Opart[((size_t)(sp * 8 + bh) * CH + c0 + c) * HW + q]);
    v[c] = s * inv;
  }
  #pragma unroll
  for (int g = 0; g < 3; ++g) {
    const int ch0 = h * CH + c0 + g * 8;
    const int kc = ch0 >> 5, off = ch0 & 31;
    unsigned short* dst = attnb + (((size_t)b * 6 + kc) * HW + q) * 32 + off;
    u16x8 gg;
    #pragma unroll
    for (int j = 0; j < 8; ++j) gg[j] = f2bf(v[g * 8 + j]);
    *(u16x8*)dst = gg;
  }
}

// ---------------------------------------------------------------------------
extern "C" void kernel_launch(void* const* d_in, const int* in_sizes, int n_in,
                              void* d_out, int out_size, void* d_ws, size_t ws_size,
                              hipStream_t stream) {
  const float* x      = (const float*)d_in[0];
  const float* qkv_w  = (const float*)d_in[1];
  const float* dw_w   = (const float*)d_in[2];
  const float* proj_w = (const float*)d_in[3];
  const float* temp   = (const float*)d_in[4];

  char* ws = (char*)d_ws;
  unsigned short* xb    = (unsigned short*)(ws);              //  3,145,728
  unsigned short* wqkv  = (unsigned short*)(ws + 3145728);    //    221,184
  unsigned short* wproj = (unsigned short*)(ws + 3366912);    //     73,728
  unsigned short* qkvb  = (unsigned short*)(ws + 3440640);    //  9,437,184
  unsigned short* dwb   = (unsigned short*)(ws + 12877824);   //  9,437,184
  unsigned short* Qr    = (unsigned short*)(ws + 22315008);   //  4,194,304
  unsigned short* Kr    = (unsigned short*)(ws + 26509312);   //  4,194,304
  unsigned short* Vs    = (unsigned short*)(ws + 30703616);   //  3,145,728
  unsigned short* Opart = (unsigned short*)(ws + 33849344);   // 12,582,912
  float*          Lpart = (float*)(ws + 46432256);            //    524,288
  unsigned short* attnb = (unsigned short*)(ws + 46956544);   //  3,145,728

  // 0) pack x + weights to chunk-major bf16
  pack2_kernel<<<dim3(67), 256, 0, stream>>>(x, qkv_w, proj_w, xb, wqkv, wproj);
  // 1) qkv 1x1 conv (bf16 MFMA GEMM, bf16 out), PF=4 -> 1152 blocks
  wx_gemm2_kernel<4, true><<<dim3(9, 64, 2), 256, 0, stream>>>(xb, wqkv, qkvb, 576);
  // 2) depthwise 3x3 (bf16 in/out)
  dw_conv3_kernel<<<dim3(1152), 256, 0, stream>>>(qkvb, dw_w, dwb);
  // 3) l2norm + temp*log2e + pack
  norm_pack3_kernel<<<dim3(16, 12, 2), 256, 0, stream>>>(dwb, temp, Qr, Kr, Vs);
  // 4) flash attention v5
  flash5_kernel<<<dim3(8, 32, KVSPLIT), 256, 0, stream>>>(Qr, Kr, Vs, temp, Opart, Lpart);
  // 4b) combine -> chunk-major attnb
  combine3_kernel<<<dim3(256), 256, 0, stream>>>(Opart, Lpart, attnb);
  // 5) proj 1x1 conv -> d_out (fp32), PF=2 -> 768 blocks
  wx_gemm2_kernel<2, false><<<dim3(3, 128, 2), 256, 0, stream>>>(attnb, wproj, (float*)d_out, 192);
}

// Round 6
// 83.826 us; speedup vs baseline: 4.2203x; 1.0137x over previous
//
#include <hip/hip_runtime.h>
#include <cstdint>
#include <cstddef>

#define HW    4096
#define IMG   64
#define DIMC  192
#define NH    4
#define CH    48
#define CPAD  64
#define KVSPLIT 4
#define NTILE (HW / 64 / KVSPLIT)
#define LOG2E 1.4426950408889634f

typedef __bf16 bf16x8 __attribute__((ext_vector_type(8)));
typedef float  f32x4  __attribute__((ext_vector_type(4)));
typedef unsigned short u16x8 __attribute__((ext_vector_type(8)));

#if __has_builtin(__builtin_amdgcn_exp2f)
#define EXP2(x) __builtin_amdgcn_exp2f(x)
#else
#define EXP2(x) exp2f(x)
#endif

__device__ __forceinline__ unsigned short f2bf(float f) {
  unsigned int u = __builtin_bit_cast(unsigned int, f);
  u = (u + 0x7FFFu + ((u >> 16) & 1u)) >> 16;   // RNE
  return (unsigned short)u;
}
__device__ __forceinline__ float bf2f(unsigned short u) {
  return __builtin_bit_cast(float, (unsigned int)u << 16);
}
__device__ __forceinline__ f32x4 mfma16(bf16x8 a, bf16x8 b, f32x4 c) {
  return __builtin_amdgcn_mfma_f32_16x16x32_bf16(a, b, c, 0, 0, 0);
}
__device__ __forceinline__ void gl16(const void* g, void* l) {
  __builtin_amdgcn_global_load_lds(
      (const __attribute__((address_space(1))) unsigned int*)g,
      (__attribute__((address_space(3))) unsigned int*)l, 16, 0, 0);
}

// ---------------------------------------------------------------------------
// P0: pack to chunk-major bf16.
//   xb:    [b][kc=6][px=4096][32]   (ch = kc*32 + j)
//   wqkv:  [kc=6][oc=576][32]
//   wproj: [kc=6][oc=192][32]
// ---------------------------------------------------------------------------
__global__ __launch_bounds__(256) void pack2_kernel(
    const float* __restrict__ x, const float* __restrict__ qkv_w,
    const float* __restrict__ proj_w, unsigned short* __restrict__ xb,
    unsigned short* __restrict__ wqkv, unsigned short* __restrict__ wproj) {
  const int bx = blockIdx.x, tid = threadIdx.x;
  if (bx < 64) {
    const int half = bx & 1;
    const int gpx = (bx >> 1) * 256 + tid;     // 0..8191
    const int b = gpx >> 12, p = gpx & 4095;
    const int ch0 = half * 96;
    const float* src = x + ((size_t)b * DIMC + ch0) * HW + p;
    #pragma unroll
    for (int kc2 = 0; kc2 < 3; ++kc2) {
      const int kc = half * 3 + kc2;
      u16x8 g[4];
      #pragma unroll
      for (int v = 0; v < 4; ++v)
        #pragma unroll
        for (int j = 0; j < 8; ++j)
          g[v][j] = f2bf(src[(size_t)(kc2 * 32 + v * 8 + j) * HW]);
      unsigned short* dst = xb + (((size_t)b * 6 + kc) * HW + p) * 32;
      #pragma unroll
      for (int v = 0; v < 4; ++v) *(u16x8*)(dst + v * 8) = g[v];
    }
  } else {
    const int row = (bx - 64) * 256 + tid;     // 0..767
    if (row < 576) {
      const float* src = qkv_w + (size_t)row * DIMC;
      #pragma unroll
      for (int kc = 0; kc < 6; ++kc) {
        u16x8 g0, g1, g2, g3;
        #pragma unroll
        for (int j = 0; j < 8; ++j) {
          g0[j] = f2bf(src[kc * 32 + j]);      g1[j] = f2bf(src[kc * 32 + 8 + j]);
          g2[j] = f2bf(src[kc * 32 + 16 + j]); g3[j] = f2bf(src[kc * 32 + 24 + j]);
        }
        unsigned short* dst = wqkv + ((size_t)kc * 576 + row) * 32;
        *(u16x8*)dst = g0; *(u16x8*)(dst + 8) = g1;
        *(u16x8*)(dst + 16) = g2; *(u16x8*)(dst + 24) = g3;
      }
    } else {
      const int oc = row - 576;                // 0..191
      const float* src = proj_w + (size_t)oc * DIMC;
      #pragma unroll
      for (int kc = 0; kc < 6; ++kc) {
        u16x8 g0, g1, g2, g3;
        #pragma unroll
        for (int j = 0; j < 8; ++j) {
          g0[j] = f2bf(src[kc * 32 + j]);      g1[j] = f2bf(src[kc * 32 + 8 + j]);
          g2[j] = f2bf(src[kc * 32 + 16 + j]); g3[j] = f2bf(src[kc * 32 + 24 + j]);
        }
        unsigned short* dst = wproj + ((size_t)kc * DIMC + oc) * 32;
        *(u16x8*)dst = g0; *(u16x8*)(dst + 8) = g1;
        *(u16x8*)(dst + 16) = g2; *(u16x8*)(dst + 24) = g3;
      }
    }
  }
}

// ---------------------------------------------------------------------------
// G1: bf16 MFMA GEMM from chunk-major layouts (all loads 1KB/wave coalesced).
// ---------------------------------------------------------------------------
template <int PF, bool OBF>
__global__ __launch_bounds__(256) void wx_gemm2_kernel(
    const unsigned short* __restrict__ xb, const unsigned short* __restrict__ wb,
    void* __restrict__ Cout, int OC) {
  const int tid = threadIdx.x;
  const int lane = tid & 63, wv = tid >> 6;
  const int l15 = lane & 15, l4 = lane >> 4;
  const int oc0 = blockIdx.x * 64 + wv * 16;
  const int px0 = blockIdx.y * (PF * 16);
  const int b   = blockIdx.z;

  f32x4 acc[PF];
  #pragma unroll
  for (int p = 0; p < PF; ++p) acc[p] = f32x4{0.f, 0.f, 0.f, 0.f};

  #pragma unroll
  for (int kc = 0; kc < 6; ++kc) {
    const bf16x8 af = *(const bf16x8*)(wb + ((size_t)kc * OC + oc0 + l15) * 32 + l4 * 8);
    const unsigned short* xrow = xb + (((size_t)b * 6 + kc) * HW + px0 + l15) * 32 + l4 * 8;
    #pragma unroll
    for (int p = 0; p < PF; ++p) {
      const bf16x8 bf = *(const bf16x8*)(xrow + p * 512);
      acc[p] = mfma16(af, bf, acc[p]);
    }
  }
  if (OBF) {
    unsigned short* Cb = (unsigned short*)Cout + ((size_t)b * OC + oc0) * HW + px0;
    #pragma unroll
    for (int p = 0; p < PF; ++p)
      #pragma unroll
      for (int r = 0; r < 4; ++r)
        Cb[(size_t)(l4 * 4 + r) * HW + p * 16 + l15] = f2bf(acc[p][r]);
  } else {
    float* Cb = (float*)Cout + ((size_t)b * OC + oc0) * HW + px0;
    #pragma unroll
    for (int p = 0; p < PF; ++p)
      #pragma unroll
      for (int r = 0; r < 4; ++r)
        Cb[(size_t)(l4 * 4 + r) * HW + p * 16 + l15] = acc[p][r];
  }
}

// ---------------------------------------------------------------------------
// K2: depthwise 3x3, bf16 in/out, fp32 LDS tile + rolling registers.
// ---------------------------------------------------------------------------
__global__ __launch_bounds__(256) void dw_conv3_kernel(
    const unsigned short* __restrict__ X, const float* __restrict__ W,
    unsigned short* __restrict__ Y) {
  __shared__ float T[66][72];
  const int bc = blockIdx.x;            // b*576 + ch
  const int ch = bc % 576;
  const int tid = threadIdx.x;
  const unsigned short* Xb = X + (size_t)bc * HW;
  #pragma unroll
  for (int i = 0; i < 4; ++i) {
    const int idx = i * 256 + tid;      // quads
    const int row = idx >> 4, c4 = (idx & 15) << 2;
    const ushort4 u = *(const ushort4*)(Xb + row * 64 + c4);
    float4 f; f.x = bf2f(u.x); f.y = bf2f(u.y); f.z = bf2f(u.z); f.w = bf2f(u.w);
    *(float4*)&T[row + 1][c4 + 4] = f;
  }
  if (tid < 72) { T[0][tid] = 0.f; T[65][tid] = 0.f; }
  if (tid >= 128 && tid < 194) { const int r = tid - 128; T[r][3] = 0.f; T[r][68] = 0.f; }
  float w[9];
  #pragma unroll
  for (int i = 0; i < 9; ++i) w[i] = W[ch * 9 + i];
  __syncthreads();

  const int xx = tid & 63, ys = (tid >> 6) << 4;
  const int c = xx + 4;
  float a0 = T[ys][c - 1],     a1 = T[ys][c],     a2 = T[ys][c + 1];
  float b0 = T[ys + 1][c - 1], b1 = T[ys + 1][c], b2 = T[ys + 1][c + 1];
  unsigned short* Yb = Y + (size_t)bc * HW;
  #pragma unroll
  for (int k = 0; k < 16; ++k) {
    const float c0 = T[ys + k + 2][c - 1], c1 = T[ys + k + 2][c], c2 = T[ys + k + 2][c + 1];
    const float s = w[0] * a0 + w[1] * a1 + w[2] * a2
                  + w[3] * b0 + w[4] * b1 + w[5] * b2
                  + w[6] * c0 + w[7] * c1 + w[8] * c2;
    Yb[(ys + k) * 64 + xx] = f2bf(s);
    a0 = b0; a1 = b1; a2 = b2; b0 = c0; b1 = c1; b2 = c2;
  }
}

// ---------------------------------------------------------------------------
// K3: l2norm + temp*log2e + pack (bf16 input), split by q/k/v section.
// Grid: (16, 12 = sel*4+h, 2).
//   Qr: [bh][p][64] linear; Kr: granule g at g^KSWZ(p); Vs: k at k^((c&7)<<3)
// ---------------------------------------------------------------------------
__global__ __launch_bounds__(256) void norm_pack3_kernel(
    const unsigned short* __restrict__ Dw, const float* __restrict__ temp,
    unsigned short* __restrict__ Qr, unsigned short* __restrict__ Kr,
    unsigned short* __restrict__ Vs) {
  const int px = blockIdx.x * 256 + threadIdx.x;
  const int sel = blockIdx.y >> 2, h = blockIdx.y & 3;
  const int b = blockIdx.z;
  const int bh = b * NH + h;
  const unsigned short* base = Dw + ((size_t)b * 576 + sel * DIMC + h * CH) * HW + px;

  float v[CH];
  if (sel == 2) {  // V: no norm
    const int kt = px & ~63, kl = px & 63;
    #pragma unroll
    for (int c = 0; c < CH; ++c)
      Vs[((size_t)bh * CH + c) * HW + kt + (kl ^ ((c & 7) << 3))] = base[(size_t)c * HW];
    return;
  }
  float ss = 0.f;
  #pragma unroll
  for (int j = 0; j < CH; ++j) { v[j] = bf2f(base[(size_t)j * HW]); ss += v[j] * v[j]; }
  const u16x8 zz = {0, 0, 0, 0, 0, 0, 0, 0};
  if (sel == 0) {  // Q: fold temperature*log2e
    const float sc = temp[h] * LOG2E / fmaxf(sqrtf(ss), 1e-12f);
    u16x8 gr[8];
    #pragma unroll
    for (int g = 0; g < 6; ++g)
      #pragma unroll
      for (int j = 0; j < 8; ++j) gr[g][j] = f2bf(v[g * 8 + j] * sc);
    gr[6] = zz; gr[7] = zz;
    unsigned short* qrow = Qr + ((size_t)bh * HW + px) * CPAD;
    #pragma unroll
    for (int g = 0; g < 8; ++g) *(u16x8*)(qrow + g * 8) = gr[g];
  } else {         // K: swizzled granules
    const int ksw = (px & 3) | (((px >> 3) & 1) << 2);
    const float sc = 1.0f / fmaxf(sqrtf(ss), 1e-12f);
    u16x8 gr[8];
    #pragma unroll
    for (int g = 0; g < 6; ++g)
      #pragma unroll
      for (int j = 0; j < 8; ++j) gr[g][j] = f2bf(v[g * 8 + j] * sc);
    gr[6] = zz; gr[7] = zz;
    unsigned short* krow = Kr + ((size_t)bh * HW + px) * CPAD;
    #pragma unroll
    for (int g = 0; g < 8; ++g) *(u16x8*)(krow + (g ^ ksw) * 8) = gr[g];
  }
}

// ---------------------------------------------------------------------------
// K4: flash attention v6: 64 queries per wave (QG=4).
// LDS ds_reads per wave-tile are independent of QG -> halving wave count
// halves LDS read traffic (the measured bottleneck). 2 blocks/CU, 256 VGPR.
//  - static softmax bound in C-init (no max tracking)
//  - exp2 via raw v_exp_f32
//  - row-sum via MFMA ones-channel (V LDS rows 48..63 const)
// Grid (8, 16, KVSPLIT=4).
// ---------------------------------------------------------------------------
__global__ __launch_bounds__(256, 2) void flash6_kernel(
    const unsigned short* __restrict__ Qr,
    const unsigned short* __restrict__ Kr,
    const unsigned short* __restrict__ Vs,
    const float* __restrict__ temp,
    unsigned short* __restrict__ Opart, float* __restrict__ Lpart) {
  __shared__ __align__(16) unsigned short Kl[2][64 * 64];   // 2 x 8KB
  __shared__ __align__(16) unsigned short Vl[2][64 * 64];   // 2 x 8KB (rows 48+: const)
  const int tid = threadIdx.x;
  const int lane = tid & 63, wv = tid >> 6;
  const int l15 = lane & 15, l4 = lane >> 4;
  const int bh = blockIdx.x, qt = blockIdx.y, sp = blockIdx.z;
  const int qb = qt * 256 + wv * 64;
  const float m = fabsf(temp[bh & 3]) * LOG2E * 1.05f + 0.1f;

  // constant rows 48..63 of V: row 48 = ones (P row-sum channel), rest zero
  for (int i = tid; i < 1024; i += 256) {
    const unsigned short vv = (i < 64) ? (unsigned short)0x3F80 : (unsigned short)0;
    Vl[0][3072 + i] = vv;
    Vl[1][3072 + i] = vv;
  }

  const unsigned short* Qb = Qr + ((size_t)bh * HW + qb) * CPAD;
  bf16x8 qf[4][2];
  #pragma unroll
  for (int qg = 0; qg < 4; ++qg)
    #pragma unroll
    for (int hh = 0; hh < 2; ++hh)
      qf[qg][hh] = *(const bf16x8*)(Qb + (size_t)(qg * 16 + l15) * CPAD + hh * 32 + l4 * 8);

  const char* kg = (const char*)Kr + ((size_t)bh * HW + (size_t)sp * (HW / KVSPLIT)) * 128;
  const char* vg = (const char*)Vs + (size_t)bh * CH * HW * 2 + (size_t)sp * (HW / KVSPLIT) * 2;
  const int koA = tid * 16;
  const int vgA = (tid >> 3) * 8192 + (tid & 7) * 16;
  const int vgB = (32 + (tid >> 3)) * 8192 + (tid & 7) * 16;

  auto stage = [&](int buf, const char* kp, const char* vp) {
    char* kl = (char*)&Kl[buf][0];
    gl16(kp + koA,        kl + koA);
    gl16(kp + 4096 + koA, kl + 4096 + koA);
    char* vl = (char*)&Vl[buf][0];
    gl16(vp + vgA, vl + tid * 16);
    if (tid < 128) gl16(vp + vgB, vl + 4096 + tid * 16);
  };

  f32x4 o[4][4];
  #pragma unroll
  for (int cg = 0; cg < 4; ++cg)
    #pragma unroll
    for (int qg = 0; qg < 4; ++qg) o[cg][qg] = f32x4{0.f, 0.f, 0.f, 0.f};
  const f32x4 zinit = {-m, -m, -m, -m};

  stage(0, kg, vg);
  kg += 8192; vg += 128;
  __syncthreads();
  int cur = 0;
  for (int t = 0; t < NTILE; ++t) {
    if (t + 1 < NTILE) { stage(cur ^ 1, kg, vg); kg += 8192; vg += 128; }
    const char* KL = (const char*)&Kl[cur][0];
    const char* VL = (const char*)&Vl[cur][0];

    // ---- S^T - m = K*Q + (-m) ----
    f32x4 s[4][4];
    __builtin_amdgcn_s_setprio(1);
    #pragma unroll
    for (int n = 0; n < 4; ++n) {
      const int row = (n >> 1) * 32 + (l15 >> 2) * 8 + (n & 1) * 4 + (l15 & 3);
      const int sw = (l15 & 7) << 4;
      const bf16x8 kf0 = *(const bf16x8*)(KL + row * 128 + ((l4 << 4) ^ sw));
      const bf16x8 kf1 = *(const bf16x8*)(KL + row * 128 + (((4 + l4) << 4) ^ sw));
      #pragma unroll
      for (int qg = 0; qg < 4; ++qg) {
        f32x4 z = mfma16(kf0, qf[qg][0], zinit);
        s[qg][n] = mfma16(kf1, qf[qg][1], z);
      }
    }
    __builtin_amdgcn_s_setprio(0);

    // ---- p = exp2(s) ----
    #pragma unroll
    for (int qg = 0; qg < 4; ++qg)
      #pragma unroll
      for (int n = 0; n < 4; ++n)
        #pragma unroll
        for (int r = 0; r < 4; ++r)
          s[qg][n][r] = EXP2(s[qg][n][r]);

    // ---- O^T += V^T * P^T (cg=3 is the ones-channel -> row sums) ----
    #pragma unroll
    for (int kc = 0; kc < 2; ++kc) {
      bf16x8 pb[4];
      #pragma unroll
      for (int qg = 0; qg < 4; ++qg)
        #pragma unroll
        for (int j = 0; j < 8; ++j)
          pb[qg][j] = (__bf16)s[qg][kc * 2 + (j >> 2)][j & 3];
      __builtin_amdgcn_s_setprio(1);
      #pragma unroll
      for (int cg = 0; cg < 4; ++cg) {
        const int vrow = cg * 16 + l15;
        const bf16x8 vf = *(const bf16x8*)(VL + vrow * 128 + (((kc * 4 + l4) ^ (l15 & 7)) << 4));
        #pragma unroll
        for (int qg = 0; qg < 4; ++qg) o[cg][qg] = mfma16(vf, pb[qg], o[cg][qg]);
      }
      __builtin_amdgcn_s_setprio(0);
    }
    __syncthreads();
    cur ^= 1;
  }

  unsigned short* Ob = Opart + (size_t)(sp * 8 + bh) * CH * HW;
  #pragma unroll
  for (int cg = 0; cg < 3; ++cg)
    #pragma unroll
    for (int qg = 0; qg < 4; ++qg)
      #pragma unroll
      for (int r = 0; r < 4; ++r)
        Ob[(size_t)(cg * 16 + l4 * 4 + r) * HW + qb + qg * 16 + l15] = f2bf(o[cg][qg][r]);
  if (l4 == 0) {
    #pragma unroll
    for (int qg = 0; qg < 4; ++qg)
      Lpart[(size_t)(sp * 8 + bh) * HW + qb + qg * 16 + l15] = o[3][qg][0];
  }
}

// ---------------------------------------------------------------------------
// K4b: combine splits -> attnb chunk-major [b][kc=6][px][32]
// Grid 256 blocks: block = (bh, 128-px group); thread = (c-half, px)
// ---------------------------------------------------------------------------
__global__ __launch_bounds__(256) void combine3_kernel(
    const unsigned short* __restrict__ Opart, const float* __restrict__ Lpart,
    unsigned short* __restrict__ attnb) {
  const int tid = threadIdx.x;
  const int bh = blockIdx.x >> 5;
  const int q  = ((blockIdx.x & 31) << 7) + (tid & 127);
  const int half = tid >> 7;
  float lsum = 0.f;
  #pragma unroll
  for (int sp = 0; sp < KVSPLIT; ++sp) lsum += Lpart[(size_t)(sp * 8 + bh) * HW + q];
  const float inv = 1.f / lsum;
  const int b = bh >> 2, h = bh & 3;
  const int c0 = half * 24;
  float v[24];
  #pragma unroll
  for (int c = 0; c < 24; ++c) {
    float s = 0.f;
    #pragma unroll
    for (int sp = 0; sp < KVSPLIT; ++sp)
      s += bf2f(Opart[((size_t)(sp * 8 + bh) * CH + c0 + c) * HW + q]);
    v[c] = s * inv;
  }
  #pragma unroll
  for (int g = 0; g < 3; ++g) {
    const int ch0 = h * CH + c0 + g * 8;
    const int kc = ch0 >> 5, off = ch0 & 31;
    unsigned short* dst = attnb + (((size_t)b * 6 + kc) * HW + q) * 32 + off;
    u16x8 gg;
    #pragma unroll
    for (int j = 0; j < 8; ++j) gg[j] = f2bf(v[g * 8 + j]);
    *(u16x8*)dst = gg;
  }
}

// ---------------------------------------------------------------------------
extern "C" void kernel_launch(void* const* d_in, const int* in_sizes, int n_in,
                              void* d_out, int out_size, void* d_ws, size_t ws_size,
                              hipStream_t stream) {
  const float* x      = (const float*)d_in[0];
  const float* qkv_w  = (const float*)d_in[1];
  const float* dw_w   = (const float*)d_in[2];
  const float* proj_w = (const float*)d_in[3];
  const float* temp   = (const float*)d_in[4];

  char* ws = (char*)d_ws;
  unsigned short* xb    = (unsigned short*)(ws);              //  3,145,728
  unsigned short* wqkv  = (unsigned short*)(ws + 3145728);    //    221,184
  unsigned short* wproj = (unsigned short*)(ws + 3366912);    //     73,728
  unsigned short* qkvb  = (unsigned short*)(ws + 3440640);    //  9,437,184
  unsigned short* dwb   = (unsigned short*)(ws + 12877824);   //  9,437,184
  unsigned short* Qr    = (unsigned short*)(ws + 22315008);   //  4,194,304
  unsigned short* Kr    = (unsigned short*)(ws + 26509312);   //  4,194,304
  unsigned short* Vs    = (unsigned short*)(ws + 30703616);   //  3,145,728
  unsigned short* Opart = (unsigned short*)(ws + 33849344);   // 12,582,912
  float*          Lpart = (float*)(ws + 46432256);            //    524,288
  unsigned short* attnb = (unsigned short*)(ws + 46956544);   //  3,145,728

  // 0) pack x + weights to chunk-major bf16
  pack2_kernel<<<dim3(67), 256, 0, stream>>>(x, qkv_w, proj_w, xb, wqkv, wproj);
  // 1) qkv 1x1 conv (bf16 MFMA GEMM, bf16 out), PF=4 -> 1152 blocks
  wx_gemm2_kernel<4, true><<<dim3(9, 64, 2), 256, 0, stream>>>(xb, wqkv, qkvb, 576);
  // 2) depthwise 3x3 (bf16 in/out)
  dw_conv3_kernel<<<dim3(1152), 256, 0, stream>>>(qkvb, dw_w, dwb);
  // 3) l2norm + temp*log2e + pack
  norm_pack3_kernel<<<dim3(16, 12, 2), 256, 0, stream>>>(dwb, temp, Qr, Kr, Vs);
  // 4) flash attention v6 (QG=4: 64 q/wave, 2 blocks/CU)
  flash6_kernel<<<dim3(8, 16, KVSPLIT), 256, 0, stream>>>(Qr, Kr, Vs, temp, Opart, Lpart);
  // 4b) combine -> chunk-major attnb
  combine3_kernel<<<dim3(256), 256, 0, stream>>>(Opart, Lpart, attnb);
  // 5) proj 1x1 conv -> d_out (fp32), PF=2 -> 768 blocks
  wx_gemm2_kernel<2, false><<<dim3(3, 128, 2), 256, 0, stream>>>(attnb, wproj, (float*)d_out, 192);
}

// Round 7
// 80.482 us; speedup vs baseline: 4.3956x; 1.0416x over previous
//
#include <hip/hip_runtime.h>
#include <cstdint>
#include <cstddef>

#define HW    4096
#define IMG   64
#define DIMC  192
#define NH    4
#define CH    48
#define CPAD  64
#define KVSPLIT 4
#define NTILE (HW / 64 / KVSPLIT)
#define LOG2E 1.4426950408889634f

typedef __bf16 bf16x8 __attribute__((ext_vector_type(8)));
typedef float  f32x4  __attribute__((ext_vector_type(4)));
typedef float  f32x16 __attribute__((ext_vector_type(16)));
typedef unsigned short u16x8 __attribute__((ext_vector_type(8)));
typedef unsigned int   u32x4 __attribute__((ext_vector_type(4)));

#if __has_builtin(__builtin_amdgcn_exp2f)
#define EXP2(x) __builtin_amdgcn_exp2f(x)
#else
#define EXP2(x) exp2f(x)
#endif

__device__ __forceinline__ unsigned short f2bf(float f) {
  unsigned int u = __builtin_bit_cast(unsigned int, f);
  u = (u + 0x7FFFu + ((u >> 16) & 1u)) >> 16;   // RNE
  return (unsigned short)u;
}
__device__ __forceinline__ float bf2f(unsigned short u) {
  return __builtin_bit_cast(float, (unsigned int)u << 16);
}
__device__ __forceinline__ f32x4 mfma16(bf16x8 a, bf16x8 b, f32x4 c) {
  return __builtin_amdgcn_mfma_f32_16x16x32_bf16(a, b, c, 0, 0, 0);
}
__device__ __forceinline__ f32x16 mfma32(bf16x8 a, bf16x8 b, f32x16 c) {
  return __builtin_amdgcn_mfma_f32_32x32x16_bf16(a, b, c, 0, 0, 0);
}
__device__ __forceinline__ void gl16(const void* g, void* l) {
  __builtin_amdgcn_global_load_lds(
      (const __attribute__((address_space(1))) unsigned int*)g,
      (__attribute__((address_space(3))) unsigned int*)l, 16, 0, 0);
}
__device__ __forceinline__ unsigned int cvtpk(float lo, float hi) {
  unsigned int d;
  asm("v_cvt_pk_bf16_f32 %0, %1, %2" : "=v"(d) : "v"(lo), "v"(hi));
  return d;
}
__device__ __forceinline__ void swap32(unsigned int& a, unsigned int& b) {
  asm("v_permlane32_swap_b32 %0, %1" : "+v"(a), "+v"(b));
}

// ---------------------------------------------------------------------------
// P0: pack to chunk-major bf16.
//   xb:    [b][kc=6][px=4096][32]; wqkv: [kc=6][oc=576][32]; wproj: [kc=6][oc=192][32]
// ---------------------------------------------------------------------------
__global__ __launch_bounds__(256) void pack2_kernel(
    const float* __restrict__ x, const float* __restrict__ qkv_w,
    const float* __restrict__ proj_w, unsigned short* __restrict__ xb,
    unsigned short* __restrict__ wqkv, unsigned short* __restrict__ wproj) {
  const int bx = blockIdx.x, tid = threadIdx.x;
  if (bx < 64) {
    const int half = bx & 1;
    const int gpx = (bx >> 1) * 256 + tid;     // 0..8191
    const int b = gpx >> 12, p = gpx & 4095;
    const int ch0 = half * 96;
    const float* src = x + ((size_t)b * DIMC + ch0) * HW + p;
    #pragma unroll
    for (int kc2 = 0; kc2 < 3; ++kc2) {
      const int kc = half * 3 + kc2;
      u16x8 g[4];
      #pragma unroll
      for (int v = 0; v < 4; ++v)
        #pragma unroll
        for (int j = 0; j < 8; ++j)
          g[v][j] = f2bf(src[(size_t)(kc2 * 32 + v * 8 + j) * HW]);
      unsigned short* dst = xb + (((size_t)b * 6 + kc) * HW + p) * 32;
      #pragma unroll
      for (int v = 0; v < 4; ++v) *(u16x8*)(dst + v * 8) = g[v];
    }
  } else {
    const int row = (bx - 64) * 256 + tid;     // 0..767
    if (row < 576) {
      const float* src = qkv_w + (size_t)row * DIMC;
      #pragma unroll
      for (int kc = 0; kc < 6; ++kc) {
        u16x8 g0, g1, g2, g3;
        #pragma unroll
        for (int j = 0; j < 8; ++j) {
          g0[j] = f2bf(src[kc * 32 + j]);      g1[j] = f2bf(src[kc * 32 + 8 + j]);
          g2[j] = f2bf(src[kc * 32 + 16 + j]); g3[j] = f2bf(src[kc * 32 + 24 + j]);
        }
        unsigned short* dst = wqkv + ((size_t)kc * 576 + row) * 32;
        *(u16x8*)dst = g0; *(u16x8*)(dst + 8) = g1;
        *(u16x8*)(dst + 16) = g2; *(u16x8*)(dst + 24) = g3;
      }
    } else {
      const int oc = row - 576;                // 0..191
      const float* src = proj_w + (size_t)oc * DIMC;
      #pragma unroll
      for (int kc = 0; kc < 6; ++kc) {
        u16x8 g0, g1, g2, g3;
        #pragma unroll
        for (int j = 0; j < 8; ++j) {
          g0[j] = f2bf(src[kc * 32 + j]);      g1[j] = f2bf(src[kc * 32 + 8 + j]);
          g2[j] = f2bf(src[kc * 32 + 16 + j]); g3[j] = f2bf(src[kc * 32 + 24 + j]);
        }
        unsigned short* dst = wproj + ((size_t)kc * DIMC + oc) * 32;
        *(u16x8*)dst = g0; *(u16x8*)(dst + 8) = g1;
        *(u16x8*)(dst + 16) = g2; *(u16x8*)(dst + 24) = g3;
      }
    }
  }
}

// ---------------------------------------------------------------------------
// G1: qkv GEMM, 192-oc blocks (3 sequential subtiles/wave) to cut B re-reads.
// Grid (3, 64, 2), PF=4, bf16 out.
// ---------------------------------------------------------------------------
__global__ __launch_bounds__(256) void qkv_gemm_kernel(
    const unsigned short* __restrict__ xb, const unsigned short* __restrict__ wb,
    unsigned short* __restrict__ Cout) {
  const int tid = threadIdx.x;
  const int lane = tid & 63, wv = tid >> 6;
  const int l15 = lane & 15, l4 = lane >> 4;
  const int ocbase = blockIdx.x * 192;
  const int px0 = blockIdx.y * 64;
  const int b   = blockIdx.z;

  f32x4 acc[3][4];
  #pragma unroll
  for (int s = 0; s < 3; ++s)
    #pragma unroll
    for (int p = 0; p < 4; ++p) acc[s][p] = f32x4{0.f, 0.f, 0.f, 0.f};

  #pragma unroll
  for (int kc = 0; kc < 6; ++kc) {
    const unsigned short* xrow = xb + (((size_t)b * 6 + kc) * HW + px0 + l15) * 32 + l4 * 8;
    bf16x8 Bf[4];
    #pragma unroll
    for (int p = 0; p < 4; ++p) Bf[p] = *(const bf16x8*)(xrow + p * 512);
    #pragma unroll
    for (int s = 0; s < 3; ++s) {
      const int oc = ocbase + s * 64 + wv * 16 + l15;
      const bf16x8 af = *(const bf16x8*)(wb + ((size_t)kc * 576 + oc) * 32 + l4 * 8);
      #pragma unroll
      for (int p = 0; p < 4; ++p) acc[s][p] = mfma16(af, Bf[p], acc[s][p]);
    }
  }
  #pragma unroll
  for (int s = 0; s < 3; ++s) {
    unsigned short* Cb = Cout + ((size_t)b * 576 + ocbase + s * 64 + wv * 16) * HW + px0;
    #pragma unroll
    for (int p = 0; p < 4; ++p)
      #pragma unroll
      for (int r = 0; r < 4; ++r)
        Cb[(size_t)(l4 * 4 + r) * HW + p * 16 + l15] = f2bf(acc[s][p][r]);
  }
}

// ---------------------------------------------------------------------------
// K2: depthwise 3x3, bf16 in/out, fp32 LDS tile + rolling registers.
// ---------------------------------------------------------------------------
__global__ __launch_bounds__(256) void dw_conv3_kernel(
    const unsigned short* __restrict__ X, const float* __restrict__ W,
    unsigned short* __restrict__ Y) {
  __shared__ float T[66][72];
  const int bc = blockIdx.x;            // b*576 + ch
  const int ch = bc % 576;
  const int tid = threadIdx.x;
  const unsigned short* Xb = X + (size_t)bc * HW;
  #pragma unroll
  for (int i = 0; i < 4; ++i) {
    const int idx = i * 256 + tid;      // quads
    const int row = idx >> 4, c4 = (idx & 15) << 2;
    const ushort4 u = *(const ushort4*)(Xb + row * 64 + c4);
    float4 f; f.x = bf2f(u.x); f.y = bf2f(u.y); f.z = bf2f(u.z); f.w = bf2f(u.w);
    *(float4*)&T[row + 1][c4 + 4] = f;
  }
  if (tid < 72) { T[0][tid] = 0.f; T[65][tid] = 0.f; }
  if (tid >= 128 && tid < 194) { const int r = tid - 128; T[r][3] = 0.f; T[r][68] = 0.f; }
  float w[9];
  #pragma unroll
  for (int i = 0; i < 9; ++i) w[i] = W[ch * 9 + i];
  __syncthreads();

  const int xx = tid & 63, ys = (tid >> 6) << 4;
  const int c = xx + 4;
  float a0 = T[ys][c - 1],     a1 = T[ys][c],     a2 = T[ys][c + 1];
  float b0 = T[ys + 1][c - 1], b1 = T[ys + 1][c], b2 = T[ys + 1][c + 1];
  unsigned short* Yb = Y + (size_t)bc * HW;
  #pragma unroll
  for (int k = 0; k < 16; ++k) {
    const float c0 = T[ys + k + 2][c - 1], c1 = T[ys + k + 2][c], c2 = T[ys + k + 2][c + 1];
    const float s = w[0] * a0 + w[1] * a1 + w[2] * a2
                  + w[3] * b0 + w[4] * b1 + w[5] * b2
                  + w[6] * c0 + w[7] * c1 + w[8] * c2;
    Yb[(ys + k) * 64 + xx] = f2bf(s);
    a0 = b0; a1 = b1; a2 = b2; b0 = c0; b1 = c1; b2 = c2;
  }
}

// ---------------------------------------------------------------------------
// K3: l2norm + temp*log2e + pack (bf16 input), split by q/k/v section.
// Grid: (16, 12 = sel*4+h, 2).
//   Qr: [bh][p][64] linear; Kr: granule g at g^KSWZ(p); Vs: k at k^((c&7)<<3)
// ---------------------------------------------------------------------------
__global__ __launch_bounds__(256) void norm_pack3_kernel(
    const unsigned short* __restrict__ Dw, const float* __restrict__ temp,
    unsigned short* __restrict__ Qr, unsigned short* __restrict__ Kr,
    unsigned short* __restrict__ Vs) {
  const int px = blockIdx.x * 256 + threadIdx.x;
  const int sel = blockIdx.y >> 2, h = blockIdx.y & 3;
  const int b = blockIdx.z;
  const int bh = b * NH + h;
  const unsigned short* base = Dw + ((size_t)b * 576 + sel * DIMC + h * CH) * HW + px;

  float v[CH];
  if (sel == 2) {  // V: no norm
    const int kt = px & ~63, kl = px & 63;
    #pragma unroll
    for (int c = 0; c < CH; ++c)
      Vs[((size_t)bh * CH + c) * HW + kt + (kl ^ ((c & 7) << 3))] = base[(size_t)c * HW];
    return;
  }
  float ss = 0.f;
  #pragma unroll
  for (int j = 0; j < CH; ++j) { v[j] = bf2f(base[(size_t)j * HW]); ss += v[j] * v[j]; }
  const u16x8 zz = {0, 0, 0, 0, 0, 0, 0, 0};
  if (sel == 0) {  // Q: fold temperature*log2e
    const float sc = temp[h] * LOG2E / fmaxf(sqrtf(ss), 1e-12f);
    u16x8 gr[8];
    #pragma unroll
    for (int g = 0; g < 6; ++g)
      #pragma unroll
      for (int j = 0; j < 8; ++j) gr[g][j] = f2bf(v[g * 8 + j] * sc);
    gr[6] = zz; gr[7] = zz;
    unsigned short* qrow = Qr + ((size_t)bh * HW + px) * CPAD;
    #pragma unroll
    for (int g = 0; g < 8; ++g) *(u16x8*)(qrow + g * 8) = gr[g];
  } else {         // K: swizzled granules
    const int ksw = (px & 3) | (((px >> 3) & 1) << 2);
    const float sc = 1.0f / fmaxf(sqrtf(ss), 1e-12f);
    u16x8 gr[8];
    #pragma unroll
    for (int g = 0; g < 6; ++g)
      #pragma unroll
      for (int j = 0; j < 8; ++j) gr[g][j] = f2bf(v[g * 8 + j] * sc);
    gr[6] = zz; gr[7] = zz;
    unsigned short* krow = Kr + ((size_t)bh * HW + px) * CPAD;
    #pragma unroll
    for (int g = 0; g < 8; ++g) *(u16x8*)(krow + (g ^ ksw) * 8) = gr[g];
  }
}

// ---------------------------------------------------------------------------
// K4: flash attention v7 — 32x32x16 MFMA.
// QK: S^T = mfma32(K, Q), K-dim=48 exact (3 chunks), 12 MFMA/wave-tile.
// PV: c padded to 64 (ones-row at c=48 inside the pad), 16 MFMA/wave-tile.
// P-fragment via cvt_pk_bf16 + permlane32_swap (lane-exact, no LDS).
// Epilogue: transpose O via LDS union -> Opart[sp][bh][q][48] bf16 + Lpart.
// Grid (8, 16, KVSPLIT=4), 2 blocks/CU.
// ---------------------------------------------------------------------------
__global__ __launch_bounds__(256, 2) void flash7_kernel(
    const unsigned short* __restrict__ Qr,
    const unsigned short* __restrict__ Kr,
    const unsigned short* __restrict__ Vs,
    const float* __restrict__ temp,
    unsigned short* __restrict__ Opart, float* __restrict__ Lpart) {
  __shared__ __align__(16) union {
    struct { unsigned short Kl[2][4096]; unsigned short Vl[2][4096]; } s;
    float T[256][53];
  } lds;
  const int tid = threadIdx.x;
  const int lane = tid & 63, wv = tid >> 6;
  const int l31 = lane & 31, lhi = lane >> 5;
  const int bh = blockIdx.x, qt = blockIdx.y, sp = blockIdx.z;
  const int qb = qt * 256 + wv * 64;
  const float m = fabsf(temp[bh & 3]) * LOG2E * 1.05f + 0.1f;

  // const rows 48..63 of V: row 48 = ones (row-sum channel), rest zero
  for (int i = tid; i < 1024; i += 256) {
    const unsigned short vv = (i < 64) ? (unsigned short)0x3F80 : (unsigned short)0;
    lds.s.Vl[0][3072 + i] = vv;
    lds.s.Vl[1][3072 + i] = vv;
  }

  // Q B-fragments: q = qb + qb2*32 + l31, ch = ci*16 + lhi*8 + j
  const unsigned short* Qb = Qr + ((size_t)bh * HW + qb) * CPAD;
  bf16x8 qf[2][3];
  #pragma unroll
  for (int qb2 = 0; qb2 < 2; ++qb2)
    #pragma unroll
    for (int ci = 0; ci < 3; ++ci)
      qf[qb2][ci] = *(const bf16x8*)(Qb + (size_t)(qb2 * 32 + l31) * CPAD + ci * 16 + lhi * 8);

  const char* kg = (const char*)Kr + ((size_t)bh * HW + (size_t)sp * (HW / KVSPLIT)) * 128;
  const char* vg = (const char*)Vs + (size_t)bh * CH * HW * 2 + (size_t)sp * (HW / KVSPLIT) * 2;
  const int koA = tid * 16;
  const int vgA = (tid >> 3) * 8192 + (tid & 7) * 16;
  const int vgB = (32 + (tid >> 3)) * 8192 + (tid & 7) * 16;

  auto stage = [&](int buf, const char* kp, const char* vp) {
    char* kl = (char*)&lds.s.Kl[buf][0];
    gl16(kp + koA,        kl + koA);
    gl16(kp + 4096 + koA, kl + 4096 + koA);
    char* vl = (char*)&lds.s.Vl[buf][0];
    gl16(vp + vgA, vl + tid * 16);
    if (tid < 128) gl16(vp + vgB, vl + 4096 + tid * 16);
  };

  f32x16 o[2][2];
  #pragma unroll
  for (int cb = 0; cb < 2; ++cb)
    #pragma unroll
    for (int qb2 = 0; qb2 < 2; ++qb2)
      #pragma unroll
      for (int i = 0; i < 16; ++i) o[cb][qb2][i] = 0.f;
  f32x16 zin;
  #pragma unroll
  for (int i = 0; i < 16; ++i) zin[i] = -m;

  stage(0, kg, vg);
  kg += 8192; vg += 128;
  __syncthreads();
  int cur = 0;
  for (int t = 0; t < NTILE; ++t) {
    if (t + 1 < NTILE) { stage(cur ^ 1, kg, vg); kg += 8192; vg += 128; }
    const unsigned short* KL = &lds.s.Kl[cur][0];
    const unsigned short* VL = &lds.s.Vl[cur][0];

    // ---- S^T - m = K*Q + (-m), 32x32x16 x3 chunks (K=48 exact) ----
    f32x16 S[2][2];
    __builtin_amdgcn_s_setprio(1);
    #pragma unroll
    for (int kb = 0; kb < 2; ++kb) {
      const int krow = kb * 32 + l31;
      const int ksw = (krow & 3) | (((krow >> 3) & 1) << 2);
      bf16x8 kf[3];
      #pragma unroll
      for (int ci = 0; ci < 3; ++ci)
        kf[ci] = *(const bf16x8*)(KL + krow * 64 + (((ci * 2 + lhi) ^ ksw) * 8));
      #pragma unroll
      for (int qb2 = 0; qb2 < 2; ++qb2) {
        f32x16 acc = zin;
        #pragma unroll
        for (int ci = 0; ci < 3; ++ci) acc = mfma32(kf[ci], qf[qb2][ci], acc);
        S[kb][qb2] = acc;
      }
    }
    __builtin_amdgcn_s_setprio(0);

    // ---- p = exp2(s) ----
    #pragma unroll
    for (int kb = 0; kb < 2; ++kb)
      #pragma unroll
      for (int qb2 = 0; qb2 < 2; ++qb2)
        #pragma unroll
        for (int i = 0; i < 16; ++i) S[kb][qb2][i] = EXP2(S[kb][qb2][i]);

    // ---- O^T += V^T * P^T, P-frag via cvt_pk + permlane32_swap ----
    #pragma unroll
    for (int kc = 0; kc < 4; ++kc) {
      const int kb = kc >> 1, rb = (kc & 1) * 8;
      bf16x8 pb[2];
      #pragma unroll
      for (int qb2 = 0; qb2 < 2; ++qb2) {
        unsigned int w0 = cvtpk(S[kb][qb2][rb + 0], S[kb][qb2][rb + 1]);
        unsigned int w1 = cvtpk(S[kb][qb2][rb + 2], S[kb][qb2][rb + 3]);
        unsigned int w2 = cvtpk(S[kb][qb2][rb + 4], S[kb][qb2][rb + 5]);
        unsigned int w3 = cvtpk(S[kb][qb2][rb + 6], S[kb][qb2][rb + 7]);
        swap32(w0, w2);
        swap32(w1, w3);
        u32x4 ww = {w0, w1, w2, w3};
        pb[qb2] = __builtin_bit_cast(bf16x8, ww);
      }
      __builtin_amdgcn_s_setprio(1);
      #pragma unroll
      for (int cb = 0; cb < 2; ++cb) {
        const int crow = cb * 32 + l31;
        const bf16x8 vf = *(const bf16x8*)(VL + crow * 64 + (((kc * 2 + lhi) ^ (crow & 7)) * 8));
        #pragma unroll
        for (int qb2 = 0; qb2 < 2; ++qb2) o[cb][qb2] = mfma32(vf, pb[qb2], o[cb][qb2]);
      }
      __builtin_amdgcn_s_setprio(0);
    }
    __syncthreads();
    cur ^= 1;
  }

  // ---- epilogue: transpose O via LDS -> Opart[q][48] bf16 + Lpart ----
  #pragma unroll
  for (int cb = 0; cb < 2; ++cb)
    #pragma unroll
    for (int qb2 = 0; qb2 < 2; ++qb2) {
      const int ql = wv * 64 + qb2 * 32 + l31;
      #pragma unroll
      for (int r = 0; r < 16; ++r) {
        const int c = cb * 32 + (r & 3) + 8 * (r >> 2) + 4 * lhi;
        if (c < 48) lds.T[ql][c] = o[cb][qb2][r];
      }
      if (lhi == 0) lds.T[ql][48] = o[1][qb2][8];   // c==48 ones-row = l
    }
  __syncthreads();
  {
    const int ql = tid;
    const int qg = qt * 256 + ql;
    float vv[48];
    #pragma unroll
    for (int c = 0; c < 48; ++c) vv[c] = lds.T[ql][c];
    const float L = lds.T[ql][48];
    unsigned short* Ob = Opart + ((size_t)(sp * 8 + bh) * HW + qg) * 48;
    #pragma unroll
    for (int g = 0; g < 6; ++g) {
      u16x8 gg;
      #pragma unroll
      for (int j = 0; j < 8; ++j) gg[j] = f2bf(vv[g * 8 + j]);
      *(u16x8*)(Ob + g * 8) = gg;
    }
    Lpart[(size_t)(sp * 8 + bh) * HW + qg] = L;
  }
}

// ---------------------------------------------------------------------------
// G2: proj GEMM with fused split-combine: B-frag = (sum_sp Opart) * inv_l.
// Opart is [sp][bh][q][48] bf16 (contiguous 8-ch runs never straddle heads).
// Grid (1, 128, 2): 192 oc via 3 subtiles/wave, PF=2. fp32 out -> d_out.
// ---------------------------------------------------------------------------
__global__ __launch_bounds__(256) void proj_gemm_kernel(
    const unsigned short* __restrict__ Opart, const float* __restrict__ Lpart,
    const unsigned short* __restrict__ wb, float* __restrict__ Cout) {
  const int tid = threadIdx.x;
  const int lane = tid & 63, wv = tid >> 6;
  const int l15 = lane & 15, l4 = lane >> 4;
  const int px0 = blockIdx.y * 32;
  const int b   = blockIdx.z;

  bf16x8 Bf[6][2];
  #pragma unroll
  for (int kc = 0; kc < 6; ++kc) {
    const int ch0 = kc * 32 + l4 * 8;
    const int head = ch0 / 48, off = ch0 % 48;
    #pragma unroll
    for (int p = 0; p < 2; ++p) {
      const int px = px0 + p * 16 + l15;
      float ls = 0.f;
      #pragma unroll
      for (int sp = 0; sp < 4; ++sp)
        ls += Lpart[(size_t)(sp * 8 + b * 4 + head) * HW + px];
      const float inv = 1.f / ls;
      float a8[8] = {};
      #pragma unroll
      for (int sp = 0; sp < 4; ++sp) {
        const u16x8 u = *(const u16x8*)(Opart +
            ((size_t)(sp * 8 + b * 4 + head) * HW + px) * 48 + off);
        #pragma unroll
        for (int j = 0; j < 8; ++j) a8[j] += bf2f(u[j]);
      }
      u16x8 g;
      #pragma unroll
      for (int j = 0; j < 8; ++j) g[j] = f2bf(a8[j] * inv);
      Bf[kc][p] = __builtin_bit_cast(bf16x8, g);
    }
  }
  #pragma unroll
  for (int s = 0; s < 3; ++s) {
    const int oc = s * 64 + wv * 16 + l15;
    f32x4 acc[2];
    #pragma unroll
    for (int p = 0; p < 2; ++p) acc[p] = f32x4{0.f, 0.f, 0.f, 0.f};
    #pragma unroll
    for (int kc = 0; kc < 6; ++kc) {
      const bf16x8 af = *(const bf16x8*)(wb + ((size_t)kc * DIMC + oc) * 32 + l4 * 8);
      #pragma unroll
      for (int p = 0; p < 2; ++p) acc[p] = mfma16(af, Bf[kc][p], acc[p]);
    }
    float* Cb = Cout + ((size_t)b * DIMC + s * 64 + wv * 16) * HW + px0;
    #pragma unroll
    for (int p = 0; p < 2; ++p)
      #pragma unroll
      for (int r = 0; r < 4; ++r)
        Cb[(size_t)(l4 * 4 + r) * HW + p * 16 + l15] = acc[p][r];
  }
}

// ---------------------------------------------------------------------------
extern "C" void kernel_launch(void* const* d_in, const int* in_sizes, int n_in,
                              void* d_out, int out_size, void* d_ws, size_t ws_size,
                              hipStream_t stream) {
  const float* x      = (const float*)d_in[0];
  const float* qkv_w  = (const float*)d_in[1];
  const float* dw_w   = (const float*)d_in[2];
  const float* proj_w = (const float*)d_in[3];
  const float* temp   = (const float*)d_in[4];

  char* ws = (char*)d_ws;
  unsigned short* xb    = (unsigned short*)(ws);              //  3,145,728
  unsigned short* wqkv  = (unsigned short*)(ws + 3145728);    //    221,184
  unsigned short* wproj = (unsigned short*)(ws + 3366912);    //     73,728
  unsigned short* qkvb  = (unsigned short*)(ws + 3440640);    //  9,437,184
  unsigned short* dwb   = (unsigned short*)(ws + 12877824);   //  9,437,184
  unsigned short* Qr    = (unsigned short*)(ws + 22315008);   //  4,194,304
  unsigned short* Kr    = (unsigned short*)(ws + 26509312);   //  4,194,304
  unsigned short* Vs    = (unsigned short*)(ws + 30703616);   //  3,145,728
  unsigned short* Opart = (unsigned short*)(ws + 33849344);   // 12,582,912  [sp][bh][q][48]
  float*          Lpart = (float*)(ws + 46432256);            //    524,288

  // 0) pack x + weights to chunk-major bf16
  pack2_kernel<<<dim3(67), 256, 0, stream>>>(x, qkv_w, proj_w, xb, wqkv, wproj);
  // 1) qkv 1x1 conv (bf16 MFMA GEMM, bf16 out), 192-oc blocks
  qkv_gemm_kernel<<<dim3(3, 64, 2), 256, 0, stream>>>(xb, wqkv, qkvb);
  // 2) depthwise 3x3 (bf16 in/out)
  dw_conv3_kernel<<<dim3(1152), 256, 0, stream>>>(qkvb, dw_w, dwb);
  // 3) l2norm + temp*log2e + pack
  norm_pack3_kernel<<<dim3(16, 12, 2), 256, 0, stream>>>(dwb, temp, Qr, Kr, Vs);
  // 4) flash attention v7 (32x32x16, [q][c] epilogue)
  flash7_kernel<<<dim3(8, 16, KVSPLIT), 256, 0, stream>>>(Qr, Kr, Vs, temp, Opart, Lpart);
  // 5) proj GEMM with fused combine -> d_out (fp32)
  proj_gemm_kernel<<<dim3(1, 128, 2), 256, 0, stream>>>(Opart, Lpart, wproj, (float*)d_out);
}